// Round 12
// baseline (954.418 us; speedup 1.0000x reference)
//
#include <hip/hip_runtime.h>

#define DIM 128
#define LSZ 100000
#define CSZ 210000
#define ESZ 630000
#define CH  16384   // ushorts per 128x128 weight chunk
#define GLT 3125    // 32-row tiles over L (exact)
#define GCT 6563    // 32-row tiles over C (last tile 16 rows)
#define MLP_NB1 125
#define MLP_NB2 262
#define MLP_NB3 125
#define MLP_NB  (MLP_NB1 + MLP_NB2 + MLP_NB3)   // 512 blocks = 2/CU

typedef __attribute__((ext_vector_type(8))) short short8;
typedef __attribute__((ext_vector_type(4))) float f32x4;

__device__ __forceinline__ ushort f2b(float x) {          // fp32 -> bf16 RNE
    unsigned u = __float_as_uint(x);
    return (ushort)((u + 0x7FFFu + ((u >> 16) & 1)) >> 16);
}
__device__ __forceinline__ float b2f(unsigned lo16) {
    return __uint_as_float(lo16 << 16);
}
__device__ __forceinline__ int lds_off(int row, int c) {
    return row * 256 + ((c ^ (row & 7)) << 4);
}
__device__ __forceinline__ void gload_lds16(const void* g, void* l) {
    __builtin_amdgcn_global_load_lds(
        (const __attribute__((address_space(1))) unsigned*)g,
        (__attribute__((address_space(3))) unsigned*)l, 16, 0, 0);
}
// REQUIRED: __syncthreads does NOT drain untracked LDS-DMA (R4/R5 evidence).
__device__ __forceinline__ void vm_drain() {
    asm volatile("s_waitcnt vmcnt(0)" ::: "memory");
}

// ======================= persistent-W mega_mlp machinery ====================
// 4-wave kloop over a 32-row X tile: wave = rows16(rh) x cols64(ch), 16 MFMA
__device__ __forceinline__ void kloop32p(const char* Xs, const char* Ws,
                                         int rh, int ch, int lane, f32x4 (&acc)[4])
{
    #pragma unroll
    for (int ks = 0; ks < 4; ++ks) {
        int kc = ks * 4 + (lane >> 4);
        short8 af = *(const short8*)(Xs + lds_off(rh * 16 + (lane & 15), kc));
        short8 bfr[4];
        #pragma unroll
        for (int n = 0; n < 4; ++n)
            bfr[n] = *(const short8*)(Ws + lds_off(ch * 64 + n * 16 + (lane & 15), kc));
        #pragma unroll
        for (int n = 0; n < 4; ++n)
            acc[n] = __builtin_amdgcn_mfma_f32_16x16x32_bf16(af, bfr[n], acc[n], 0, 0, 0);
    }
}
// 32-row X tile via DMA, 4 waves
__device__ __forceinline__ void stage_x32_4w(const ushort* __restrict__ G, size_t grow0,
                                             char* L, int wid, int lane, bool swap)
{
    #pragma unroll
    for (int g = 0; g < 2; ++g) {
        int row0 = wid * 8 + g * 4;
        int row  = row0 + (lane >> 4);
        size_t grow = grow0 + (size_t)(swap ? (row ^ 1) : row);
        const ushort* src = G + grow * DIM + (((lane & 15) ^ (row & 7)) << 3);
        gload_lds16(src, L + row0 * 256);
    }
}
// 32-row boundary tile via registers (256 threads)
__device__ __forceinline__ void stage_x32_slow4(const ushort* __restrict__ X, int r0t,
                                                char* Xs, int tid, int M, bool swap)
{
    #pragma unroll
    for (int i = 0; i < 2; ++i) {
        int id = i * 256 + tid;
        int row = id >> 4, c = id & 15;
        int gr = r0t + row;
        short8 v = {0,0,0,0,0,0,0,0};
        if (gr < M) {
            int sr = swap ? (gr ^ 1) : gr;
            v = *(const short8*)(X + (size_t)sr * DIM + c * 8);
        }
        *(short8*)(Xs + lds_off(row, c)) = v;
    }
}
// 128x128 W tile via DMA, 4 waves
__device__ __forceinline__ void stage_w128_4w(const ushort* __restrict__ G, char* L,
                                              int wid, int lane)
{
    #pragma unroll
    for (int g = 0; g < 8; ++g) {
        int row0 = wid * 32 + g * 4;
        int row  = row0 + (lane >> 4);
        const ushort* src = G + (size_t)row * DIM + (((lane & 15) ^ (row & 7)) << 3);
        gload_lds16(src, L + row0 * 256);
    }
}

// Persistent-W, X-double-buffered fused 2-layer MLP over a chunk of tiles.
__launch_bounds__(256)
__global__ void mega_mlp(const ushort* __restrict__ l_in, const ushort* __restrict__ c_in,
                         const ushort* __restrict__ Wt,
                         const float* __restrict__ l2c_b1, const float* __restrict__ l2c_b2,
                         const float* __restrict__ c2l_b1, const float* __restrict__ c2l_b2,
                         const float* __restrict__ l2l_b1, const float* __restrict__ l2l_b2,
                         ushort* __restrict__ A_bf, ushort* __restrict__ B_bf,
                         ushort* __restrict__ L2L_bf,
                         const float* __restrict__ c_att, const float* __restrict__ l_att,
                         float* __restrict__ ql1, float* __restrict__ qc2)
{
    __shared__ char smem[81920];            // 32K W1 + 32K W2 + 2 x 8K Xbuf = 80KB
    char* W1s = smem;
    char* W2s = smem + 32768;
    char* Xb0 = smem + 65536;
    char* Xb1 = smem + 73728;

    int b = blockIdx.x;
    const ushort *X, *Wt1, *Wt2;
    const float *b1, *b2, *attp;
    ushort* Yb; float* dotout;
    int M, t0, t1; bool swap, dot;
    if (b < MLP_NB1) {
        X = l_in; Wt1 = Wt + 0 * CH; Wt2 = Wt + 1 * CH; b1 = l2c_b1; b2 = l2c_b2;
        Yb = A_bf; attp = c_att + DIM; dotout = ql1; M = LSZ; swap = false; dot = true;
        int cpb = (GLT + MLP_NB1 - 1) / MLP_NB1;
        t0 = b * cpb; t1 = min(t0 + cpb, GLT);
    } else if (b < MLP_NB1 + MLP_NB2) {
        int bb = b - MLP_NB1;
        X = c_in; Wt1 = Wt + 2 * CH; Wt2 = Wt + 3 * CH; b1 = c2l_b1; b2 = c2l_b2;
        Yb = B_bf; attp = l_att + DIM; dotout = qc2; M = CSZ; swap = false; dot = true;
        int cpb = (GCT + MLP_NB2 - 1) / MLP_NB2;
        t0 = bb * cpb; t1 = min(t0 + cpb, GCT);
    } else {
        int bb = b - MLP_NB1 - MLP_NB2;
        X = l_in; Wt1 = Wt + 4 * CH; Wt2 = Wt + 5 * CH; b1 = l2l_b1; b2 = l2l_b2;
        Yb = L2L_bf; attp = nullptr; dotout = nullptr; M = LSZ; swap = true; dot = false;
        int cpb = (GLT + MLP_NB3 - 1) / MLP_NB3;
        t0 = bb * cpb; t1 = min(t0 + cpb, GLT);
    }
    if (t0 >= t1) return;

    const int tid  = threadIdx.x;
    const int lane = tid & 63;
    const int wid  = tid >> 6;              // 0..3
    const int rh = wid & 1, ch = wid >> 1;
    const int col0 = ch * 64 + (lane & 15);

    // one-time: stage both weight tiles + first X tile
    stage_w128_4w(Wt1, W1s, wid, lane);
    stage_w128_4w(Wt2, W2s, wid, lane);
    bool full0 = (t0 * 32 + 32 <= M);
    if (full0) stage_x32_4w(X, (size_t)t0 * 32, Xb0, wid, lane, swap);
    vm_drain();
    __syncthreads();
    if (!full0) { stage_x32_slow4(X, t0 * 32, Xb0, tid, M, swap); __syncthreads(); }

    float b1v[4], b2v[4], attv[4];
    #pragma unroll
    for (int n = 0; n < 4; ++n) {
        b1v[n] = b1[col0 + n * 16];
        b2v[n] = b2[col0 + n * 16];
        if (dot) attv[n] = attp[col0 + n * 16];
    }

    char* cur = Xb0; char* nxt = Xb1;
    for (int t = t0; t < t1; ++t) {
        int r0t = t * 32;
        bool haveNext = (t + 1 < t1);
        int r0n = (t + 1) * 32;
        bool fullNext = haveNext && (r0n + 32 <= M);
        if (fullNext) stage_x32_4w(X, (size_t)r0n, nxt, wid, lane, swap);  // overlapped DMA

        f32x4 acc[4];
        #pragma unroll
        for (int n = 0; n < 4; ++n) acc[n] = (f32x4){0.f, 0.f, 0.f, 0.f};
        kloop32p(cur, W1s, rh, ch, lane, acc);
        __syncthreads();                    // all waves done reading cur as X

        #pragma unroll
        for (int i = 0; i < 4; ++i) {       // H = relu(acc+b1) bf16 into cur (swizzled)
            int row = rh * 16 + (lane >> 4) * 4 + i;
            #pragma unroll
            for (int n = 0; n < 4; ++n) {
                float v = fmaxf(acc[n][i] + b1v[n], 0.f);
                int cb = (col0 + n * 16) * 2;
                *(ushort*)(cur + row * 256 + (((cb >> 4) ^ (row & 7)) << 4) + (cb & 15)) = f2b(v);
            }
        }
        __syncthreads();                    // H published

        #pragma unroll
        for (int n = 0; n < 4; ++n) acc[n] = (f32x4){0.f, 0.f, 0.f, 0.f};
        kloop32p(cur, W2s, rh, ch, lane, acc);

        float ps[4];
        #pragma unroll
        for (int i = 0; i < 4; ++i) {
            int gr = r0t + rh * 16 + (lane >> 4) * 4 + i;
            float p = 0.f;
            #pragma unroll
            for (int n = 0; n < 4; ++n) {
                float y = acc[n][i] + b2v[n];
                if (gr < M) Yb[(size_t)gr * DIM + col0 + n * 16] = f2b(y);
                if (dot) p = fmaf(y, attv[n], p);
            }
            ps[i] = p;
        }
        if (dot) {
            #pragma unroll
            for (int mask = 1; mask <= 8; mask <<= 1)
                #pragma unroll
                for (int i = 0; i < 4; ++i)
                    ps[i] += __shfl_xor(ps[i], mask);
            if ((lane & 15) == 0) {
                #pragma unroll
                for (int i = 0; i < 4; ++i) {
                    int gr = r0t + rh * 16 + (lane >> 4) * 4 + i;
                    if (gr < M) atomicAdd(dotout + gr, ps[i]);  // 2 adds/row (col halves)
                }
            }
        }
        if (haveNext && !fullNext) stage_x32_slow4(X, r0n, nxt, tid, M, swap);
        vm_drain();                         // X(t+1) DMA landed (covered by compute)
        __syncthreads();
        char* tmp = cur; cur = nxt; nxt = tmp;
    }
}

// ======================= R9-champion upd machinery (unchanged) ==============
__device__ __forceinline__ void kloop64(const char* Xs, const char* Ws,
                                        int wr, int wc, int lane, f32x4 (&acc)[2][4])
{
    #pragma unroll
    for (int ks = 0; ks < 4; ++ks) {
        int kc = ks * 4 + (lane >> 4);
        short8 af[2], bfr[4];
        #pragma unroll
        for (int m = 0; m < 2; ++m) {
            int row = wr * 32 + m * 16 + (lane & 15);
            af[m] = *(const short8*)(Xs + lds_off(row, kc));
        }
        #pragma unroll
        for (int n = 0; n < 4; ++n) {
            int col = wc * 64 + n * 16 + (lane & 15);
            bfr[n] = *(const short8*)(Ws + lds_off(col, kc));
        }
        #pragma unroll
        for (int m = 0; m < 2; ++m)
            #pragma unroll
            for (int n = 0; n < 4; ++n)
                acc[m][n] = __builtin_amdgcn_mfma_f32_16x16x32_bf16(af[m], bfr[n], acc[m][n], 0, 0, 0);
    }
}

__device__ __forceinline__ void stage_x64(const ushort* __restrict__ G, size_t grow0,
                                          char* L, int wid, int lane)
{
    #pragma unroll
    for (int g = 0; g < 4; ++g) {
        int row0 = wid * 16 + g * 4;
        int row  = row0 + (lane >> 4);
        const ushort* src = G + (grow0 + (size_t)row) * DIM + (((lane & 15) ^ (row & 7)) << 3);
        gload_lds16(src, L + row0 * 256);
    }
}

__device__ __forceinline__ void stage_w128(const ushort* __restrict__ G, char* L,
                                           int wid, int lane)
{
    #pragma unroll
    for (int g = 0; g < 8; ++g) {
        int row0 = wid * 32 + g * 4;
        int row  = row0 + (lane >> 4);
        const ushort* src = G + (size_t)row * DIM + (((lane & 15) ^ (row & 7)) << 3);
        gload_lds16(src, L + row0 * 256);
    }
}

__device__ __forceinline__ void stage_x64_slow(const ushort* __restrict__ X, int r0t,
                                               char* Xs, int tid, int M)
{
    #pragma unroll
    for (int i = 0; i < 4; ++i) {
        int id = i * 256 + tid;
        int row = id >> 4, c = id & 15;
        int gr = r0t + row;
        short8 v = {0,0,0,0,0,0,0,0};
        if (gr < M) v = *(const short8*)(X + (size_t)gr * DIM + c * 8);
        *(short8*)(Xs + lds_off(row, c)) = v;
    }
}

__device__ __forceinline__ void stage_w_slow(const ushort* __restrict__ W, char* Ws, int tid)
{
    #pragma unroll
    for (int i = 0; i < 8; ++i) {
        int id = i * 256 + tid;
        int row = id >> 4, c = id & 15;
        *(short8*)(Ws + lds_off(row, c)) = *(const short8*)(W + row * DIM + c * 8);
    }
}

__device__ __forceinline__ void upd_body(char* smem, int bloc,
    const ushort* __restrict__ X1, const ushort* __restrict__ X2, const ushort* __restrict__ X3,
    int nin, const ushort* __restrict__ Wt, const float* __restrict__ bias,
    float* __restrict__ Yf, ushort* __restrict__ Ybm,
    const float* __restrict__ attp, float* __restrict__ dotout,
    int M, bool writebf, bool dot)
{
    char* Xs = smem;
    char* Ws = smem + 16384;
    const int tid  = threadIdx.x;
    const int lane = tid & 63;
    const int wid  = tid >> 6;
    const int wr = wid >> 1, wc = wid & 1;
    const int r0t = bloc * 64;
    const bool full = (r0t + 64 <= M);

    f32x4 acc[2][4];
    #pragma unroll
    for (int m = 0; m < 2; ++m)
        #pragma unroll
        for (int n = 0; n < 4; ++n) acc[m][n] = (f32x4){0.f, 0.f, 0.f, 0.f};

    for (int in = 0; in < nin; ++in) {
        const ushort* X = (in == 0) ? X1 : ((in == 1) ? X2 : X3);
        __syncthreads();
        if (full) {
            stage_x64(X, (size_t)r0t, Xs, wid, lane);
            stage_w128(Wt + (size_t)in * CH, Ws, wid, lane);
            vm_drain();
        } else {
            stage_x64_slow(X, r0t, Xs, tid, M);
            stage_w_slow(Wt + (size_t)in * CH, Ws, tid);
        }
        __syncthreads();
        kloop64(Xs, Ws, wr, wc, lane, acc);
    }

    const int col0 = wc * 64 + (lane & 15);
    float bv[4], attv[4];
    #pragma unroll
    for (int n = 0; n < 4; ++n) bv[n] = bias[col0 + n * 16];
    if (dot)
        #pragma unroll
        for (int n = 0; n < 4; ++n) attv[n] = attp[col0 + n * 16];

    float ps[2][4];
    #pragma unroll
    for (int m = 0; m < 2; ++m)
        #pragma unroll
        for (int i = 0; i < 4; ++i) {
            int gr = r0t + wr * 32 + m * 16 + (lane >> 4) * 4 + i;
            float p = 0.f;
            #pragma unroll
            for (int n = 0; n < 4; ++n) {
                float v = acc[m][n][i] + bv[n];
                if (gr < M) {
                    Yf[(size_t)gr * DIM + col0 + n * 16] = v;
                    if (writebf) Ybm[(size_t)gr * DIM + col0 + n * 16] = f2b(v);
                }
                if (dot) p = fmaf(v, attv[n], p);
            }
            ps[m][i] = p;
        }

    if (dot) {
        #pragma unroll
        for (int mask = 1; mask <= 8; mask <<= 1)
            #pragma unroll
            for (int m = 0; m < 2; ++m)
                #pragma unroll
                for (int i = 0; i < 4; ++i)
                    ps[m][i] += __shfl_xor(ps[m][i], mask);
        __syncthreads();
        float* part = (float*)smem;
        if ((lane & 15) == 0)
            #pragma unroll
            for (int m = 0; m < 2; ++m)
                #pragma unroll
                for (int i = 0; i < 4; ++i)
                    part[wc * 64 + wr * 32 + m * 16 + (lane >> 4) * 4 + i] = ps[m][i];
        __syncthreads();
        if (tid < 64) {
            int gr = r0t + tid;
            if (gr < M) dotout[gr] = part[tid] + part[64 + tid];
        }
    }
}

__launch_bounds__(256)
__global__ void mega_upd(const ushort* __restrict__ c_in, const ushort* __restrict__ AGC,
                         const ushort* __restrict__ l_in, const ushort* __restrict__ AGL,
                         const ushort* __restrict__ L2L,
                         const ushort* __restrict__ Wt,
                         const float* __restrict__ c_upd_b, const float* __restrict__ l_upd_b,
                         float* __restrict__ outCf, ushort* __restrict__ c_bf1,
                         float* __restrict__ outLf, ushort* __restrict__ l_bf1,
                         const float* __restrict__ c_att, const float* __restrict__ l_att,
                         float* __restrict__ pc1, float* __restrict__ pl2,
                         int GC, int GL, int flags)
{
    __shared__ char smem[49152];
    int b = blockIdx.x;
    bool wb = flags != 0;
    if (b < GC) {
        upd_body(smem, b, c_in, AGC, nullptr, 2, Wt + 6 * CH, c_upd_b,
                 outCf, c_bf1, c_att, pc1, CSZ, wb, wb);
    } else {
        upd_body(smem, b - GC, l_in, AGL, L2L, 3, Wt + 8 * CH, l_upd_b,
                 outLf, l_bf1, l_att, pl2, LSZ, wb, wb);
    }
}

// ---------------------------------------------------------------------------
// one-time converts
// ---------------------------------------------------------------------------
__launch_bounds__(256)
__global__ void wtrans_all(const float* __restrict__ w0, const float* __restrict__ w1,
                           const float* __restrict__ w2, const float* __restrict__ w3,
                           const float* __restrict__ w4, const float* __restrict__ w5,
                           const float* __restrict__ wcu, const float* __restrict__ wlu,
                           ushort* __restrict__ Wt)
{
    int ch = blockIdx.y;
    const float* W;
    if      (ch == 0) W = w0;
    else if (ch == 1) W = w1;
    else if (ch == 2) W = w2;
    else if (ch == 3) W = w3;
    else if (ch == 4) W = w4;
    else if (ch == 5) W = w5;
    else if (ch == 6) W = wcu;
    else if (ch == 7) W = wcu + 16384;
    else if (ch == 8) W = wlu;
    else if (ch == 9) W = wlu + 16384;
    else              W = wlu + 32768;
    int idx = blockIdx.x * 256 + threadIdx.x;
    int k = idx >> 7, c = idx & 127;
    Wt[(size_t)ch * CH + c * 128 + k] = f2b(W[k * 128 + c]);
}

__launch_bounds__(256)
__global__ void cvt_dot2(const float* __restrict__ l_emb, const float* __restrict__ c_emb,
                         ushort* __restrict__ l_bf, ushort* __restrict__ c_bf,
                         float* __restrict__ outLf, float* __restrict__ outCf,
                         const float* __restrict__ l_att, const float* __restrict__ c_att,
                         float* __restrict__ pl2, float* __restrict__ pc1, int GLW)
{
    int b = blockIdx.x;
    int wid = threadIdx.x >> 6;
    int lane = threadIdx.x & 63;
    const float* in; ushort* obf; float* of32; const float* att; float* dout; int M; int w;
    if (b < GLW) { in = l_emb; obf = l_bf; of32 = outLf; att = l_att; dout = pl2; M = LSZ; w = b * 4 + wid; }
    else         { in = c_emb; obf = c_bf; of32 = outCf; att = c_att; dout = pc1; M = CSZ; w = (b - GLW) * 4 + wid; }
    if (w >= M) return;
    float2 v = *(const float2*)(in + (size_t)w * DIM + lane * 2);
    *(float2*)(of32 + (size_t)w * DIM + lane * 2) = v;
    ushort ba = f2b(v.x), bb = f2b(v.y);
    *(unsigned*)(obf + (size_t)w * DIM + lane * 2) = (unsigned)ba | ((unsigned)bb << 16);
    float2 a = *(const float2*)(att + lane * 2);
    float s = b2f(ba) * a.x + b2f(bb) * a.y;
    #pragma unroll
    for (int k = 32; k >= 1; k >>= 1) s += __shfl_xor(s, k);
    if (lane == 0) dout[w] = s;
}

// ---------------------------------------------------------------------------
// CSR build
// ---------------------------------------------------------------------------
__launch_bounds__(256)
__global__ void hist_kernel(const int* __restrict__ le, const int* __restrict__ ce,
                            unsigned* __restrict__ cnt_comb)
{
    int e = blockIdx.x * blockDim.x + threadIdx.x;
    if (e >= ESZ) return;
    atomicAdd(cnt_comb + ce[e], 1u);
    atomicAdd(cnt_comb + CSZ + le[e], 1u);
}

__launch_bounds__(256)
__global__ void scan_partial(const unsigned* __restrict__ in, unsigned* __restrict__ out,
                             unsigned* __restrict__ bsum, int n)
{
    __shared__ unsigned s[256];
    int tid  = threadIdx.x;
    int base = blockIdx.x * 1024 + tid * 4;
    unsigned v[4];
    #pragma unroll
    for (int k = 0; k < 4; ++k) v[k] = (base + k < n) ? in[base + k] : 0u;
    unsigned tsum = v[0] + v[1] + v[2] + v[3];
    s[tid] = tsum;
    __syncthreads();
    for (int off = 1; off < 256; off <<= 1) {
        unsigned t = (tid >= off) ? s[tid - off] : 0u;
        __syncthreads();
        s[tid] += t;
        __syncthreads();
    }
    unsigned run = s[tid] - tsum;
    #pragma unroll
    for (int k = 0; k < 4; ++k) {
        if (base + k < n) out[base + k] = run;
        run += v[k];
    }
    if (tid == 255) bsum[blockIdx.x] = s[255];
}

__launch_bounds__(256)
__global__ void scan_top(unsigned* __restrict__ bsum, int nb)
{
    __shared__ unsigned s[512];
    int tid = threadIdx.x;
    unsigned v0 = (tid < nb) ? bsum[tid] : 0u;
    unsigned v1 = (tid + 256 < nb) ? bsum[tid + 256] : 0u;
    s[tid] = v0; s[tid + 256] = v1;
    __syncthreads();
    for (int off = 1; off < 512; off <<= 1) {
        unsigned t0 = (tid >= off) ? s[tid - off] : 0u;
        unsigned t1 = (tid + 256 >= off) ? s[tid + 256 - off] : 0u;
        __syncthreads();
        s[tid] += t0; s[tid + 256] += t1;
        __syncthreads();
    }
    if (tid < nb) bsum[tid] = s[tid] - v0;
    if (tid + 256 < nb) bsum[tid + 256] = s[tid + 256] - v1;
}

__launch_bounds__(256)
__global__ void scan_fixup(const unsigned* __restrict__ scr, const unsigned* __restrict__ bsum,
                           unsigned* __restrict__ base_c, unsigned* __restrict__ base_l,
                           unsigned* __restrict__ cur_c, unsigned* __restrict__ cur_l)
{
    int i = blockIdx.x * blockDim.x + threadIdx.x;
    int n = CSZ + LSZ;
    if (i < n) {
        unsigned v = scr[i] + bsum[i >> 10];
        if (i < CSZ) { base_c[i] = v; cur_c[i] = v; }
        else { unsigned b = v - ESZ; base_l[i - CSZ] = b; cur_l[i - CSZ] = b; }
    }
    if (i == 0) { base_c[CSZ] = ESZ; base_l[LSZ] = ESZ; }
}

__launch_bounds__(256)
__global__ void scatter_kernel(const int* __restrict__ le, const int* __restrict__ ce,
                               unsigned* __restrict__ cur_c, unsigned* __restrict__ cur_l,
                               unsigned* __restrict__ perm_c, unsigned* __restrict__ perm_l,
                               unsigned* __restrict__ le_csr, unsigned* __restrict__ ce_csr)
{
    int e = blockIdx.x * blockDim.x + threadIdx.x;
    if (e >= ESZ) return;
    int lv = le[e], cv = ce[e];
    unsigned p1 = atomicAdd(cur_c + cv, 1u);
    perm_c[p1] = (unsigned)e;
    le_csr[p1] = (unsigned)lv;
    unsigned p2 = atomicAdd(cur_l + lv, 1u);
    perm_l[p2] = (unsigned)e;
    ce_csr[p2] = (unsigned)cv;
}

// ---------------------------------------------------------------------------
// thread-per-clause fused score + leaky-relu + segment softmax
// ---------------------------------------------------------------------------
__launch_bounds__(256)
__global__ void fused_softmax(const unsigned* __restrict__ base_c, const unsigned* __restrict__ le_csr,
                              const unsigned* __restrict__ perm_c,
                              const float* __restrict__ pc1, const float* __restrict__ ql1,
                              const float* __restrict__ pl2, const float* __restrict__ qc2,
                              float* __restrict__ W1csr, float* __restrict__ W2e,
                              float* __restrict__ D1, float* __restrict__ D2)
{
    int c = blockIdx.x * blockDim.x + threadIdx.x;
    if (c >= CSZ) return;
    unsigned b0 = base_c[c], b1 = base_c[c + 1];
    float pc = pc1[c], qc = qc2[c];
    float m1 = -1e30f, m2 = -1e30f;
    for (unsigned j = b0; j < b1; ++j) {
        unsigned lv = le_csr[j];
        float s1 = pc + ql1[lv];  s1 = (s1 > 0.f) ? s1 : 0.2f * s1;
        float s2 = pl2[lv] + qc;  s2 = (s2 > 0.f) ? s2 : 0.2f * s2;
        m1 = fmaxf(m1, s1);
        m2 = fmaxf(m2, s2);
    }
    float d1 = 0.f, d2 = 0.f;
    for (unsigned j = b0; j < b1; ++j) {
        unsigned lv = le_csr[j];
        float s1 = pc + ql1[lv];  s1 = (s1 > 0.f) ? s1 : 0.2f * s1;
        float s2 = pl2[lv] + qc;  s2 = (s2 > 0.f) ? s2 : 0.2f * s2;
        float ex1 = __expf(s1 - m1);
        float ex2 = __expf(s2 - m2);
        d1 += ex1; d2 += ex2;
        W1csr[j] = ex1;
        W2e[perm_c[j]] = ex2;
    }
    D1[c] = d1; D2[c] = d2;
}

// ---------------------------------------------------------------------------
// MEGA dispatch 2: aggr_c and aggr_l in one grid (wave per node)
// ---------------------------------------------------------------------------
__launch_bounds__(256)
__global__ void mega_aggr(const unsigned* __restrict__ base_c, const unsigned* __restrict__ le_csr,
                          const float* __restrict__ W1csr, const float* __restrict__ D1,
                          const ushort* __restrict__ A_bf, ushort* __restrict__ AGC,
                          const unsigned* __restrict__ base_l, const unsigned* __restrict__ ce_csr,
                          const unsigned* __restrict__ perm_l,
                          const float* __restrict__ W2e, const float* __restrict__ D2,
                          const ushort* __restrict__ B_bf, ushort* __restrict__ AGL,
                          int GCW)
{
    int b = blockIdx.x;
    int wid = threadIdx.x >> 6;
    int lane = threadIdx.x & 63;
    int d = lane * 2;
    if (b < GCW) {
        int w = b * 4 + wid;
        if (w >= CSZ) return;
        unsigned b0 = base_c[w], b1 = base_c[w + 1];
        float invd = 1.f / (D1[w] + 1e-16f);
        float ax = 0.f, ay = 0.f;
        for (unsigned j = b0; j < b1; ++j) {
            float wt = W1csr[j] * invd;
            unsigned lv = le_csr[j];
            unsigned av = *(const unsigned*)(A_bf + (size_t)lv * DIM + d);
            ax = fmaf(wt, b2f(av & 0xffffu), ax);
            ay = fmaf(wt, b2f(av >> 16), ay);
        }
        *(unsigned*)(AGC + (size_t)w * DIM + d) = (unsigned)f2b(ax) | ((unsigned)f2b(ay) << 16);
    } else {
        int w = (b - GCW) * 4 + wid;
        if (w >= LSZ) return;
        unsigned b0 = base_l[w], b1 = base_l[w + 1];
        float ax = 0.f, ay = 0.f;
        for (unsigned j = b0; j < b1; ++j) {
            unsigned e = perm_l[j];
            unsigned cv = ce_csr[j];
            float wt = W2e[e] / (D2[cv] + 1e-16f);
            unsigned bv = *(const unsigned*)(B_bf + (size_t)cv * DIM + d);
            ax = fmaf(wt, b2f(bv & 0xffffu), ax);
            ay = fmaf(wt, b2f(bv >> 16), ay);
        }
        *(unsigned*)(AGL + (size_t)w * DIM + d) = (unsigned)f2b(ax) | ((unsigned)f2b(ay) << 16);
    }
}

extern "C" void kernel_launch(void* const* d_in, const int* in_sizes, int n_in,
                              void* d_out, int out_size, void* d_ws, size_t ws_size,
                              hipStream_t stream)
{
    const int*   le      = (const int*)  d_in[2];
    const int*   ce      = (const int*)  d_in[3];
    const float* l_emb0  = (const float*)d_in[4];
    const float* c_emb0  = (const float*)d_in[5];
    const float* l2c_w1  = (const float*)d_in[6];
    const float* l2c_b1  = (const float*)d_in[7];
    const float* l2c_w2  = (const float*)d_in[8];
    const float* l2c_b2  = (const float*)d_in[9];
    const float* c2l_w1  = (const float*)d_in[10];
    const float* c2l_b1  = (const float*)d_in[11];
    const float* c2l_w2  = (const float*)d_in[12];
    const float* c2l_b2  = (const float*)d_in[13];
    const float* l2l_w1  = (const float*)d_in[14];
    const float* l2l_b1  = (const float*)d_in[15];
    const float* l2l_w2  = (const float*)d_in[16];
    const float* l2l_b2  = (const float*)d_in[17];
    const float* c_att   = (const float*)d_in[18];
    const float* c_upd_w = (const float*)d_in[19];
    const float* c_upd_b = (const float*)d_in[20];
    const float* l_att   = (const float*)d_in[21];
    const float* l_upd_w = (const float*)d_in[22];
    const float* l_upd_b = (const float*)d_in[23];

    float* out = (float*)d_out;
    float* outL[3] = { out,
                       out + (size_t)LSZ * DIM,
                       out + 2 * (size_t)LSZ * DIM };
    float* outC[3] = { out + 3 * (size_t)LSZ * DIM,
                       out + 3 * (size_t)LSZ * DIM + (size_t)CSZ * DIM,
                       out + 3 * (size_t)LSZ * DIM + 2 * (size_t)CSZ * DIM };

    char* p = (char*)d_ws;
    ushort* A_bf   = (ushort*)p; p += (size_t)LSZ * DIM * 2;
    ushort* B_bf   = (ushort*)p; p += (size_t)CSZ * DIM * 2;
    ushort* AGC_bf = (ushort*)p; p += (size_t)CSZ * DIM * 2;
    ushort* AGL_bf = (ushort*)p; p += (size_t)LSZ * DIM * 2;
    ushort* L2L_bf = (ushort*)p; p += (size_t)LSZ * DIM * 2;
    ushort* l_bf0  = (ushort*)p; p += (size_t)LSZ * DIM * 2;
    ushort* l_bf1  = (ushort*)p; p += (size_t)LSZ * DIM * 2;
    ushort* c_bf0  = (ushort*)p; p += (size_t)CSZ * DIM * 2;
    ushort* c_bf1  = (ushort*)p; p += (size_t)CSZ * DIM * 2;
    ushort* Wt     = (ushort*)p; p += (size_t)11 * CH * 2;
    float* W1csr = (float*)p; p += (size_t)ESZ * 4;
    float* W2e   = (float*)p; p += (size_t)ESZ * 4;
    float* pc1 = (float*)p; p += (size_t)CSZ * 4;
    float* qc2 = (float*)p; p += (size_t)CSZ * 4;
    float* ql1 = (float*)p; p += (size_t)LSZ * 4;
    float* pl2 = (float*)p; p += (size_t)LSZ * 4;
    float* D1  = (float*)p; p += (size_t)CSZ * 4;
    float* D2  = (float*)p; p += (size_t)CSZ * 4;
    unsigned* base_c   = (unsigned*)p; p += (size_t)(CSZ + 1) * 4;
    unsigned* base_l   = (unsigned*)p; p += (size_t)(LSZ + 1) * 4;
    unsigned* cur_c    = (unsigned*)p; p += (size_t)CSZ * 4;
    unsigned* cur_l    = (unsigned*)p; p += (size_t)LSZ * 4;
    unsigned* cnt_comb = (unsigned*)p; p += (size_t)(CSZ + LSZ) * 4;
    unsigned* scr_comb = (unsigned*)p; p += (size_t)(CSZ + LSZ) * 4;
    unsigned* perm_c = (unsigned*)p; p += (size_t)ESZ * 4;
    unsigned* perm_l = (unsigned*)p; p += (size_t)ESZ * 4;
    unsigned* le_csr = (unsigned*)p; p += (size_t)ESZ * 4;
    unsigned* ce_csr = (unsigned*)p; p += (size_t)ESZ * 4;
    unsigned* bsum   = (unsigned*)p; p += 1024 * 4;

    const int GL64 = (LSZ + 63) / 64;
    const int GC64 = (CSZ + 63) / 64;
    const int GE_THR = (ESZ + 255) / 256;
    const int GC_THR = (CSZ + 255) / 256;
    const int GC_WAVE = (CSZ + 3) / 4;
    const int GL_WAVE = (LSZ + 3) / 4;
    const int NCOMB = CSZ + LSZ;

    // preamble: converts + iter-0 dots, weights, CSR build
    cvt_dot2<<<GL_WAVE + GC_WAVE, 256, 0, stream>>>(l_emb0, c_emb0, l_bf0, c_bf0,
                                                    outL[0], outC[0], l_att, c_att,
                                                    pl2, pc1, GL_WAVE);
    wtrans_all<<<dim3(64, 11), 256, 0, stream>>>(l2c_w1, l2c_w2, c2l_w1, c2l_w2,
                                                 l2l_w1, l2l_w2, c_upd_w, l_upd_w, Wt);
    hipMemsetAsync(cnt_comb, 0, (size_t)NCOMB * sizeof(unsigned), stream);
    hist_kernel<<<GE_THR, 256, 0, stream>>>(le, ce, cnt_comb);
    int nb = (NCOMB + 1023) / 1024;
    scan_partial<<<nb, 256, 0, stream>>>(cnt_comb, scr_comb, bsum, NCOMB);
    scan_top<<<1, 256, 0, stream>>>(bsum, nb);
    scan_fixup<<<(NCOMB + 255) / 256, 256, 0, stream>>>(scr_comb, bsum, base_c, base_l, cur_c, cur_l);
    scatter_kernel<<<GE_THR, 256, 0, stream>>>(le, ce, cur_c, cur_l, perm_c, perm_l, le_csr, ce_csr);

    for (int it = 0; it < 2; ++it) {
        const ushort* l_in = (it == 0) ? l_bf0 : l_bf1;
        const ushort* c_in = (it == 0) ? c_bf0 : c_bf1;

        // qc2|ql1 are adjacent in ws: one fused zero for the atomic dot outputs
        hipMemsetAsync(qc2, 0, (size_t)(CSZ + LSZ) * sizeof(float), stream);

        mega_mlp<<<MLP_NB, 256, 0, stream>>>(
            l_in, c_in, Wt, l2c_b1, l2c_b2, c2l_b1, c2l_b2, l2l_b1, l2l_b2,
            A_bf, B_bf, L2L_bf, c_att, l_att, ql1, qc2);

        fused_softmax<<<GC_THR, 256, 0, stream>>>(base_c, le_csr, perm_c,
                                                  pc1, ql1, pl2, qc2, W1csr, W2e, D1, D2);

        mega_aggr<<<GC_WAVE + GL_WAVE, 256, 0, stream>>>(
            base_c, le_csr, W1csr, D1, A_bf, AGC_bf,
            base_l, ce_csr, perm_l, W2e, D2, B_bf, AGL_bf, GC_WAVE);

        mega_upd<<<GC64 + GL64, 256, 0, stream>>>(
            c_in, AGC_bf, l_in, AGL_bf, L2L_bf, Wt, c_upd_b, l_upd_b,
            outC[it + 1], c_bf1, outL[it + 1], l_bf1,
            c_att, l_att, pc1, pl2, GC64, GL64, (it == 0) ? 1 : 0);
    }
}

// Round 13
// 904.869 us; speedup vs baseline: 1.0548x; 1.0548x over previous
//
#include <hip/hip_runtime.h>

#define DIM 128
#define LSZ 100000
#define CSZ 210000
#define ESZ 630000
#define CH  16384   // ushorts per 128x128 weight chunk

typedef __attribute__((ext_vector_type(8))) short short8;
typedef __attribute__((ext_vector_type(4))) float f32x4;

__device__ __forceinline__ ushort f2b(float x) {          // fp32 -> bf16 RNE
    unsigned u = __float_as_uint(x);
    return (ushort)((u + 0x7FFFu + ((u >> 16) & 1)) >> 16);
}
__device__ __forceinline__ float b2f(unsigned lo16) {
    return __uint_as_float(lo16 << 16);
}
__device__ __forceinline__ int lds_off(int row, int c) {
    return row * 256 + ((c ^ (row & 7)) << 4);
}
__device__ __forceinline__ void gload_lds16(const void* g, void* l) {
    __builtin_amdgcn_global_load_lds(
        (const __attribute__((address_space(1))) unsigned*)g,
        (__attribute__((address_space(3))) unsigned*)l, 16, 0, 0);
}
// REQUIRED before any __syncthreads() that publishes LDS-DMA results.
__device__ __forceinline__ void vm_drain() {
    asm volatile("s_waitcnt vmcnt(0)" ::: "memory");
}

// K=128 inner loop over a 64-row X tile: acc[2][4], 32 MFMA/wave
__device__ __forceinline__ void kloop64(const char* Xs, const char* Ws,
                                        int wr, int wc, int lane, f32x4 (&acc)[2][4])
{
    #pragma unroll
    for (int ks = 0; ks < 4; ++ks) {
        int kc = ks * 4 + (lane >> 4);
        short8 af[2], bfr[4];
        #pragma unroll
        for (int m = 0; m < 2; ++m) {
            int row = wr * 32 + m * 16 + (lane & 15);
            af[m] = *(const short8*)(Xs + lds_off(row, kc));
        }
        #pragma unroll
        for (int n = 0; n < 4; ++n) {
            int col = wc * 64 + n * 16 + (lane & 15);
            bfr[n] = *(const short8*)(Ws + lds_off(col, kc));
        }
        #pragma unroll
        for (int m = 0; m < 2; ++m)
            #pragma unroll
            for (int n = 0; n < 4; ++n)
                acc[m][n] = __builtin_amdgcn_mfma_f32_16x16x32_bf16(af[m], bfr[n], acc[m][n], 0, 0, 0);
    }
}

// stage 64x128 X tile via LDS-DMA (16KB), source pre-swizzled; runtime row-swap
__device__ __forceinline__ void stage_x64(const ushort* __restrict__ G, size_t grow0,
                                          char* L, int wid, int lane, bool swap)
{
    #pragma unroll
    for (int g = 0; g < 4; ++g) {
        int row0 = wid * 16 + g * 4;
        int row  = row0 + (lane >> 4);
        size_t grow = grow0 + (size_t)(swap ? (row ^ 1) : row);
        const ushort* src = G + grow * DIM + (((lane & 15) ^ (row & 7)) << 3);
        gload_lds16(src, L + row0 * 256);
    }
}

// stage 128x128 weight tile via LDS-DMA (32KB)
__device__ __forceinline__ void stage_w128(const ushort* __restrict__ G, char* L,
                                           int wid, int lane)
{
    #pragma unroll
    for (int g = 0; g < 8; ++g) {
        int row0 = wid * 32 + g * 4;
        int row  = row0 + (lane >> 4);
        const ushort* src = G + (size_t)row * DIM + (((lane & 15) ^ (row & 7)) << 3);
        gload_lds16(src, L + row0 * 256);
    }
}

// register-staged boundary X tile (64 rows) with bounds check
__device__ __forceinline__ void stage_x64_slow(const ushort* __restrict__ X, int r0t,
                                               char* Xs, int tid, int M, bool swap)
{
    #pragma unroll
    for (int i = 0; i < 4; ++i) {
        int id = i * 256 + tid;            // 0..1023
        int row = id >> 4, c = id & 15;
        int gr = r0t + row;
        short8 v = {0,0,0,0,0,0,0,0};
        if (gr < M) {
            int sr = swap ? (gr ^ 1) : gr;
            v = *(const short8*)(X + (size_t)sr * DIM + c * 8);
        }
        *(short8*)(Xs + lds_off(row, c)) = v;
    }
}

// register-staged weight tile (always full 128 rows)
__device__ __forceinline__ void stage_w_slow(const ushort* __restrict__ W, char* Ws, int tid)
{
    #pragma unroll
    for (int i = 0; i < 8; ++i) {
        int id = i * 256 + tid;
        int row = id >> 4, c = id & 15;
        *(short8*)(Ws + lds_off(row, c)) = *(const short8*)(W + row * DIM + c * 8);
    }
}

// ---------------------------------------------------------------------------
// 2-layer MLP body, 64-row tile (48KB LDS -> 3 blocks/CU)
// ---------------------------------------------------------------------------
__device__ __forceinline__ void mlp2_body(char* smem, int bloc,
    const ushort* __restrict__ X,
    const ushort* __restrict__ Wt1, const ushort* __restrict__ Wt2,
    const float* __restrict__ b1, const float* __restrict__ b2,
    ushort* __restrict__ Yb,
    const float* __restrict__ attp, float* __restrict__ dotout,
    int M, bool swap, bool dot)
{
    char* Xs = smem;                       // 16KB
    char* Ws = smem + 16384;               // 32KB
    const int tid  = threadIdx.x;
    const int lane = tid & 63;
    const int wid  = tid >> 6;
    const int wr = wid >> 1, wc = wid & 1;
    const int r0t = bloc * 64;
    const bool full = (r0t + 64 <= M);

    if (full) {
        stage_x64(X, (size_t)r0t, Xs, wid, lane, swap);
        stage_w128(Wt1, Ws, wid, lane);
        vm_drain();
    } else {
        stage_x64_slow(X, r0t, Xs, tid, M, swap);
        stage_w_slow(Wt1, Ws, tid);
    }
    __syncthreads();

    f32x4 acc[2][4];
    #pragma unroll
    for (int m = 0; m < 2; ++m)
        #pragma unroll
        for (int n = 0; n < 4; ++n) acc[m][n] = (f32x4){0.f, 0.f, 0.f, 0.f};

    kloop64(Xs, Ws, wr, wc, lane, acc);
    __syncthreads();                       // all LDS reads of X/W1 done

    // stage W2 via DMA; write H = relu(acc+b1) bf16 into Xs
    stage_w128(Wt2, Ws, wid, lane);
    {
        const int col0 = wc * 64 + (lane & 15);
        float b1v[4];
        #pragma unroll
        for (int n = 0; n < 4; ++n) b1v[n] = b1[col0 + n * 16];
        #pragma unroll
        for (int m = 0; m < 2; ++m)
            #pragma unroll
            for (int i = 0; i < 4; ++i) {
                int row = wr * 32 + m * 16 + (lane >> 4) * 4 + i;
                #pragma unroll
                for (int n = 0; n < 4; ++n) {
                    float v = fmaxf(acc[m][n][i] + b1v[n], 0.f);
                    int cb = (col0 + n * 16) * 2;
                    *(ushort*)(Xs + row * 256 + (((cb >> 4) ^ (row & 7)) << 4) + (cb & 15)) = f2b(v);
                }
            }
    }
    vm_drain();
    __syncthreads();

    #pragma unroll
    for (int m = 0; m < 2; ++m)
        #pragma unroll
        for (int n = 0; n < 4; ++n) acc[m][n] = (f32x4){0.f, 0.f, 0.f, 0.f};

    kloop64(Xs, Ws, wr, wc, lane, acc);

    const int col0 = wc * 64 + (lane & 15);
    float b2v[4], attv[4];
    #pragma unroll
    for (int n = 0; n < 4; ++n) b2v[n] = b2[col0 + n * 16];
    if (dot)
        #pragma unroll
        for (int n = 0; n < 4; ++n) attv[n] = attp[col0 + n * 16];

    float ps[2][4];
    #pragma unroll
    for (int m = 0; m < 2; ++m)
        #pragma unroll
        for (int i = 0; i < 4; ++i) {
            int gr = r0t + wr * 32 + m * 16 + (lane >> 4) * 4 + i;
            float p = 0.f;
            #pragma unroll
            for (int n = 0; n < 4; ++n) {
                float y = acc[m][n][i] + b2v[n];
                if (gr < M) Yb[(size_t)gr * DIM + col0 + n * 16] = f2b(y);
                if (dot) p = fmaf(y, attv[n], p);
            }
            ps[m][i] = p;
        }

    if (dot) {
        #pragma unroll
        for (int mask = 1; mask <= 8; mask <<= 1)
            #pragma unroll
            for (int m = 0; m < 2; ++m)
                #pragma unroll
                for (int i = 0; i < 4; ++i)
                    ps[m][i] += __shfl_xor(ps[m][i], mask);
        __syncthreads();
        float* part = (float*)smem;        // [2][64]
        if ((lane & 15) == 0)
            #pragma unroll
            for (int m = 0; m < 2; ++m)
                #pragma unroll
                for (int i = 0; i < 4; ++i)
                    part[wc * 64 + wr * 32 + m * 16 + (lane >> 4) * 4 + i] = ps[m][i];
        __syncthreads();
        if (tid < 64) {
            int gr = r0t + tid;
            if (gr < M) dotout[gr] = part[tid] + part[64 + tid];
        }
    }
}

// ---------------------------------------------------------------------------
// concat-K update GEMM body, 64-row tile; fp32 d_out via nontemporal stores
// ---------------------------------------------------------------------------
__device__ __forceinline__ void upd_body(char* smem, int bloc,
    const ushort* __restrict__ X1, const ushort* __restrict__ X2, const ushort* __restrict__ X3,
    int nin, const ushort* __restrict__ Wt, const float* __restrict__ bias,
    float* __restrict__ Yf, ushort* __restrict__ Ybm,
    const float* __restrict__ attp, float* __restrict__ dotout,
    int M, bool writebf, bool dot)
{
    char* Xs = smem;
    char* Ws = smem + 16384;
    const int tid  = threadIdx.x;
    const int lane = tid & 63;
    const int wid  = tid >> 6;
    const int wr = wid >> 1, wc = wid & 1;
    const int r0t = bloc * 64;
    const bool full = (r0t + 64 <= M);

    f32x4 acc[2][4];
    #pragma unroll
    for (int m = 0; m < 2; ++m)
        #pragma unroll
        for (int n = 0; n < 4; ++n) acc[m][n] = (f32x4){0.f, 0.f, 0.f, 0.f};

    for (int in = 0; in < nin; ++in) {
        const ushort* X = (in == 0) ? X1 : ((in == 1) ? X2 : X3);
        __syncthreads();                   // previous kloop's LDS reads done
        if (full) {
            stage_x64(X, (size_t)r0t, Xs, wid, lane, false);
            stage_w128(Wt + (size_t)in * CH, Ws, wid, lane);
            vm_drain();
        } else {
            stage_x64_slow(X, r0t, Xs, tid, M, false);
            stage_w_slow(Wt + (size_t)in * CH, Ws, tid);
        }
        __syncthreads();
        kloop64(Xs, Ws, wr, wc, lane, acc);
    }

    const int col0 = wc * 64 + (lane & 15);
    float bv[4], attv[4];
    #pragma unroll
    for (int n = 0; n < 4; ++n) bv[n] = bias[col0 + n * 16];
    if (dot)
        #pragma unroll
        for (int n = 0; n < 4; ++n) attv[n] = attp[col0 + n * 16];

    float ps[2][4];
    #pragma unroll
    for (int m = 0; m < 2; ++m)
        #pragma unroll
        for (int i = 0; i < 4; ++i) {
            int gr = r0t + wr * 32 + m * 16 + (lane >> 4) * 4 + i;
            float p = 0.f;
            #pragma unroll
            for (int n = 0; n < 4; ++n) {
                float v = acc[m][n][i] + bv[n];
                if (gr < M) {
                    __builtin_nontemporal_store(v, &Yf[(size_t)gr * DIM + col0 + n * 16]);
                    if (writebf) Ybm[(size_t)gr * DIM + col0 + n * 16] = f2b(v);
                }
                if (dot) p = fmaf(v, attv[n], p);
            }
            ps[m][i] = p;
        }

    if (dot) {
        #pragma unroll
        for (int mask = 1; mask <= 8; mask <<= 1)
            #pragma unroll
            for (int m = 0; m < 2; ++m)
                #pragma unroll
                for (int i = 0; i < 4; ++i)
                    ps[m][i] += __shfl_xor(ps[m][i], mask);
        __syncthreads();
        float* part = (float*)smem;
        if ((lane & 15) == 0)
            #pragma unroll
            for (int m = 0; m < 2; ++m)
                #pragma unroll
                for (int i = 0; i < 4; ++i)
                    part[wc * 64 + wr * 32 + m * 16 + (lane >> 4) * 4 + i] = ps[m][i];
        __syncthreads();
        if (tid < 64) {
            int gr = r0t + tid;
            if (gr < M) dotout[gr] = part[tid] + part[64 + tid];
        }
    }
}

// ---------------------------------------------------------------------------
// MEGA dispatch 1: all three message MLPs in one grid
// ---------------------------------------------------------------------------
__launch_bounds__(256)
__global__ void mega_mlp(const ushort* __restrict__ l_in, const ushort* __restrict__ c_in,
                         const ushort* __restrict__ Wt,
                         const float* __restrict__ l2c_b1, const float* __restrict__ l2c_b2,
                         const float* __restrict__ c2l_b1, const float* __restrict__ c2l_b2,
                         const float* __restrict__ l2l_b1, const float* __restrict__ l2l_b2,
                         ushort* __restrict__ A_bf, ushort* __restrict__ B_bf,
                         ushort* __restrict__ L2L_bf,
                         const float* __restrict__ c_att, const float* __restrict__ l_att,
                         float* __restrict__ ql1, float* __restrict__ qc2,
                         int GL, int GC)
{
    __shared__ char smem[49152];
    int b = blockIdx.x;
    if (b < GL) {
        mlp2_body(smem, b, l_in, Wt + 0 * CH, Wt + 1 * CH, l2c_b1, l2c_b2,
                  A_bf, c_att + DIM, ql1, LSZ, false, true);
    } else if (b < GL + GC) {
        mlp2_body(smem, b - GL, c_in, Wt + 2 * CH, Wt + 3 * CH, c2l_b1, c2l_b2,
                  B_bf, l_att + DIM, qc2, CSZ, false, true);
    } else {
        mlp2_body(smem, b - GL - GC, l_in, Wt + 4 * CH, Wt + 5 * CH, l2l_b1, l2l_b2,
                  L2L_bf, nullptr, nullptr, LSZ, true, false);
    }
}

// ---------------------------------------------------------------------------
// MEGA dispatch 3: both update GEMMs in one grid
// ---------------------------------------------------------------------------
__launch_bounds__(256)
__global__ void mega_upd(const ushort* __restrict__ c_in, const ushort* __restrict__ AGC,
                         const ushort* __restrict__ l_in, const ushort* __restrict__ AGL,
                         const ushort* __restrict__ L2L,
                         const ushort* __restrict__ Wt,
                         const float* __restrict__ c_upd_b, const float* __restrict__ l_upd_b,
                         float* __restrict__ outCf, ushort* __restrict__ c_bf1,
                         float* __restrict__ outLf, ushort* __restrict__ l_bf1,
                         const float* __restrict__ c_att, const float* __restrict__ l_att,
                         float* __restrict__ pc1, float* __restrict__ pl2,
                         int GC, int GL, int flags)   // flags!=0 -> writebf+dot
{
    __shared__ char smem[49152];
    int b = blockIdx.x;
    bool wb = flags != 0;
    if (b < GC) {
        upd_body(smem, b, c_in, AGC, nullptr, 2, Wt + 6 * CH, c_upd_b,
                 outCf, c_bf1, c_att, pc1, CSZ, wb, wb);
    } else {
        upd_body(smem, b - GC, l_in, AGL, L2L, 3, Wt + 8 * CH, l_upd_b,
                 outLf, l_bf1, l_att, pl2, LSZ, wb, wb);
    }
}

// ---------------------------------------------------------------------------
// one-time converts
// ---------------------------------------------------------------------------
__launch_bounds__(256)
__global__ void wtrans_all(const float* __restrict__ w0, const float* __restrict__ w1,
                           const float* __restrict__ w2, const float* __restrict__ w3,
                           const float* __restrict__ w4, const float* __restrict__ w5,
                           const float* __restrict__ wcu, const float* __restrict__ wlu,
                           ushort* __restrict__ Wt)
{
    int ch = blockIdx.y;
    const float* W;
    if      (ch == 0) W = w0;
    else if (ch == 1) W = w1;
    else if (ch == 2) W = w2;
    else if (ch == 3) W = w3;
    else if (ch == 4) W = w4;
    else if (ch == 5) W = w5;
    else if (ch == 6) W = wcu;
    else if (ch == 7) W = wcu + 16384;
    else if (ch == 8) W = wlu;
    else if (ch == 9) W = wlu + 16384;
    else              W = wlu + 32768;
    int idx = blockIdx.x * 256 + threadIdx.x;
    int k = idx >> 7, c = idx & 127;
    Wt[(size_t)ch * CH + c * 128 + k] = f2b(W[k * 128 + c]);
}

// merged L+C: fp32 copy (NT) to d_out slot0 + bf16 convert + attention dot
__launch_bounds__(256)
__global__ void cvt_dot2(const float* __restrict__ l_emb, const float* __restrict__ c_emb,
                         ushort* __restrict__ l_bf, ushort* __restrict__ c_bf,
                         float* __restrict__ outLf, float* __restrict__ outCf,
                         const float* __restrict__ l_att, const float* __restrict__ c_att,
                         float* __restrict__ pl2, float* __restrict__ pc1, int GLW)
{
    int b = blockIdx.x;
    int wid = threadIdx.x >> 6;
    int lane = threadIdx.x & 63;
    const float* in; ushort* obf; float* of32; const float* att; float* dout; int M; int w;
    if (b < GLW) { in = l_emb; obf = l_bf; of32 = outLf; att = l_att; dout = pl2; M = LSZ; w = b * 4 + wid; }
    else         { in = c_emb; obf = c_bf; of32 = outCf; att = c_att; dout = pc1; M = CSZ; w = (b - GLW) * 4 + wid; }
    if (w >= M) return;
    float2 v = *(const float2*)(in + (size_t)w * DIM + lane * 2);
    __builtin_nontemporal_store(v.x, of32 + (size_t)w * DIM + lane * 2);
    __builtin_nontemporal_store(v.y, of32 + (size_t)w * DIM + lane * 2 + 1);
    ushort ba = f2b(v.x), bb = f2b(v.y);
    *(unsigned*)(obf + (size_t)w * DIM + lane * 2) = (unsigned)ba | ((unsigned)bb << 16);
    float2 a = *(const float2*)(att + lane * 2);
    float s = b2f(ba) * a.x + b2f(bb) * a.y;
    #pragma unroll
    for (int k = 32; k >= 1; k >>= 1) s += __shfl_xor(s, k);
    if (lane == 0) dout[w] = s;
}

// ---------------------------------------------------------------------------
// CSR build
// ---------------------------------------------------------------------------
__launch_bounds__(256)
__global__ void hist_kernel(const int* __restrict__ le, const int* __restrict__ ce,
                            unsigned* __restrict__ cnt_comb)
{
    int e = blockIdx.x * blockDim.x + threadIdx.x;
    if (e >= ESZ) return;
    atomicAdd(cnt_comb + ce[e], 1u);
    atomicAdd(cnt_comb + CSZ + le[e], 1u);
}

__launch_bounds__(256)
__global__ void scan_partial(const unsigned* __restrict__ in, unsigned* __restrict__ out,
                             unsigned* __restrict__ bsum, int n)
{
    __shared__ unsigned s[256];
    int tid  = threadIdx.x;
    int base = blockIdx.x * 1024 + tid * 4;
    unsigned v[4];
    #pragma unroll
    for (int k = 0; k < 4; ++k) v[k] = (base + k < n) ? in[base + k] : 0u;
    unsigned tsum = v[0] + v[1] + v[2] + v[3];
    s[tid] = tsum;
    __syncthreads();
    for (int off = 1; off < 256; off <<= 1) {
        unsigned t = (tid >= off) ? s[tid - off] : 0u;
        __syncthreads();
        s[tid] += t;
        __syncthreads();
    }
    unsigned run = s[tid] - tsum;
    #pragma unroll
    for (int k = 0; k < 4; ++k) {
        if (base + k < n) out[base + k] = run;
        run += v[k];
    }
    if (tid == 255) bsum[blockIdx.x] = s[255];
}

__launch_bounds__(256)
__global__ void scan_top(unsigned* __restrict__ bsum, int nb)
{
    __shared__ unsigned s[512];
    int tid = threadIdx.x;
    unsigned v0 = (tid < nb) ? bsum[tid] : 0u;
    unsigned v1 = (tid + 256 < nb) ? bsum[tid + 256] : 0u;
    s[tid] = v0; s[tid + 256] = v1;
    __syncthreads();
    for (int off = 1; off < 512; off <<= 1) {
        unsigned t0 = (tid >= off) ? s[tid - off] : 0u;
        unsigned t1 = (tid + 256 >= off) ? s[tid + 256 - off] : 0u;
        __syncthreads();
        s[tid] += t0; s[tid + 256] += t1;
        __syncthreads();
    }
    if (tid < nb) bsum[tid] = s[tid] - v0;
    if (tid + 256 < nb) bsum[tid + 256] = s[tid + 256] - v1;
}

__launch_bounds__(256)
__global__ void scan_fixup(const unsigned* __restrict__ scr, const unsigned* __restrict__ bsum,
                           unsigned* __restrict__ base_c, unsigned* __restrict__ base_l,
                           unsigned* __restrict__ cur_c, unsigned* __restrict__ cur_l)
{
    int i = blockIdx.x * blockDim.x + threadIdx.x;
    int n = CSZ + LSZ;
    if (i < n) {
        unsigned v = scr[i] + bsum[i >> 10];
        if (i < CSZ) { base_c[i] = v; cur_c[i] = v; }
        else { unsigned b = v - ESZ; base_l[i - CSZ] = b; cur_l[i - CSZ] = b; }
    }
    if (i == 0) { base_c[CSZ] = ESZ; base_l[LSZ] = ESZ; }
}

__launch_bounds__(256)
__global__ void scatter_kernel(const int* __restrict__ le, const int* __restrict__ ce,
                               unsigned* __restrict__ cur_c, unsigned* __restrict__ cur_l,
                               unsigned* __restrict__ perm_c, unsigned* __restrict__ perm_l,
                               unsigned* __restrict__ le_csr, unsigned* __restrict__ ce_csr)
{
    int e = blockIdx.x * blockDim.x + threadIdx.x;
    if (e >= ESZ) return;
    int lv = le[e], cv = ce[e];
    unsigned p1 = atomicAdd(cur_c + cv, 1u);
    perm_c[p1] = (unsigned)e;
    le_csr[p1] = (unsigned)lv;
    unsigned p2 = atomicAdd(cur_l + lv, 1u);
    perm_l[p2] = (unsigned)e;
    ce_csr[p2] = (unsigned)cv;
}

// ---------------------------------------------------------------------------
// thread-per-clause fused score + leaky-relu + segment softmax
// ---------------------------------------------------------------------------
__launch_bounds__(256)
__global__ void fused_softmax(const unsigned* __restrict__ base_c, const unsigned* __restrict__ le_csr,
                              const unsigned* __restrict__ perm_c,
                              const float* __restrict__ pc1, const float* __restrict__ ql1,
                              const float* __restrict__ pl2, const float* __restrict__ qc2,
                              float* __restrict__ W1csr, float* __restrict__ W2e,
                              float* __restrict__ D1, float* __restrict__ D2)
{
    int c = blockIdx.x * blockDim.x + threadIdx.x;
    if (c >= CSZ) return;
    unsigned b0 = base_c[c], b1 = base_c[c + 1];
    float pc = pc1[c], qc = qc2[c];
    float m1 = -1e30f, m2 = -1e30f;
    for (unsigned j = b0; j < b1; ++j) {
        unsigned lv = le_csr[j];
        float s1 = pc + ql1[lv];  s1 = (s1 > 0.f) ? s1 : 0.2f * s1;
        float s2 = pl2[lv] + qc;  s2 = (s2 > 0.f) ? s2 : 0.2f * s2;
        m1 = fmaxf(m1, s1);
        m2 = fmaxf(m2, s2);
    }
    float d1 = 0.f, d2 = 0.f;
    for (unsigned j = b0; j < b1; ++j) {
        unsigned lv = le_csr[j];
        float s1 = pc + ql1[lv];  s1 = (s1 > 0.f) ? s1 : 0.2f * s1;
        float s2 = pl2[lv] + qc;  s2 = (s2 > 0.f) ? s2 : 0.2f * s2;
        float ex1 = __expf(s1 - m1);
        float ex2 = __expf(s2 - m2);
        d1 += ex1; d2 += ex2;
        W1csr[j] = ex1;
        W2e[perm_c[j]] = ex2;
    }
    D1[c] = d1; D2[c] = d2;
}

// ---------------------------------------------------------------------------
// MEGA dispatch 2: aggr_c and aggr_l in one grid (wave per node)
// ---------------------------------------------------------------------------
__launch_bounds__(256)
__global__ void mega_aggr(const unsigned* __restrict__ base_c, const unsigned* __restrict__ le_csr,
                          const float* __restrict__ W1csr, const float* __restrict__ D1,
                          const ushort* __restrict__ A_bf, ushort* __restrict__ AGC,
                          const unsigned* __restrict__ base_l, const unsigned* __restrict__ ce_csr,
                          const unsigned* __restrict__ perm_l,
                          const float* __restrict__ W2e, const float* __restrict__ D2,
                          const ushort* __restrict__ B_bf, ushort* __restrict__ AGL,
                          int GCW)
{
    int b = blockIdx.x;
    int wid = threadIdx.x >> 6;
    int lane = threadIdx.x & 63;
    int d = lane * 2;
    if (b < GCW) {
        int w = b * 4 + wid;
        if (w >= CSZ) return;
        unsigned b0 = base_c[w], b1 = base_c[w + 1];
        float invd = 1.f / (D1[w] + 1e-16f);
        float ax = 0.f, ay = 0.f;
        for (unsigned j = b0; j < b1; ++j) {
            float wt = W1csr[j] * invd;
            unsigned lv = le_csr[j];
            unsigned av = *(const unsigned*)(A_bf + (size_t)lv * DIM + d);
            ax = fmaf(wt, b2f(av & 0xffffu), ax);
            ay = fmaf(wt, b2f(av >> 16), ay);
        }
        *(unsigned*)(AGC + (size_t)w * DIM + d) = (unsigned)f2b(ax) | ((unsigned)f2b(ay) << 16);
    } else {
        int w = (b - GCW) * 4 + wid;
        if (w >= LSZ) return;
        unsigned b0 = base_l[w], b1 = base_l[w + 1];
        float ax = 0.f, ay = 0.f;
        for (unsigned j = b0; j < b1; ++j) {
            unsigned e = perm_l[j];
            unsigned cv = ce_csr[j];
            float wt = W2e[e] / (D2[cv] + 1e-16f);
            unsigned bv = *(const unsigned*)(B_bf + (size_t)cv * DIM + d);
            ax = fmaf(wt, b2f(bv & 0xffffu), ax);
            ay = fmaf(wt, b2f(bv >> 16), ay);
        }
        *(unsigned*)(AGL + (size_t)w * DIM + d) = (unsigned)f2b(ax) | ((unsigned)f2b(ay) << 16);
    }
}

extern "C" void kernel_launch(void* const* d_in, const int* in_sizes, int n_in,
                              void* d_out, int out_size, void* d_ws, size_t ws_size,
                              hipStream_t stream)
{
    const int*   le      = (const int*)  d_in[2];
    const int*   ce      = (const int*)  d_in[3];
    const float* l_emb0  = (const float*)d_in[4];
    const float* c_emb0  = (const float*)d_in[5];
    const float* l2c_w1  = (const float*)d_in[6];
    const float* l2c_b1  = (const float*)d_in[7];
    const float* l2c_w2  = (const float*)d_in[8];
    const float* l2c_b2  = (const float*)d_in[9];
    const float* c2l_w1  = (const float*)d_in[10];
    const float* c2l_b1  = (const float*)d_in[11];
    const float* c2l_w2  = (const float*)d_in[12];
    const float* c2l_b2  = (const float*)d_in[13];
    const float* l2l_w1  = (const float*)d_in[14];
    const float* l2l_b1  = (const float*)d_in[15];
    const float* l2l_w2  = (const float*)d_in[16];
    const float* l2l_b2  = (const float*)d_in[17];
    const float* c_att   = (const float*)d_in[18];
    const float* c_upd_w = (const float*)d_in[19];
    const float* c_upd_b = (const float*)d_in[20];
    const float* l_att   = (const float*)d_in[21];
    const float* l_upd_w = (const float*)d_in[22];
    const float* l_upd_b = (const float*)d_in[23];

    float* out = (float*)d_out;
    float* outL[3] = { out,
                       out + (size_t)LSZ * DIM,
                       out + 2 * (size_t)LSZ * DIM };
    float* outC[3] = { out + 3 * (size_t)LSZ * DIM,
                       out + 3 * (size_t)LSZ * DIM + (size_t)CSZ * DIM,
                       out + 3 * (size_t)LSZ * DIM + 2 * (size_t)CSZ * DIM };

    char* p = (char*)d_ws;
    ushort* A_bf   = (ushort*)p; p += (size_t)LSZ * DIM * 2;
    ushort* B_bf   = (ushort*)p; p += (size_t)CSZ * DIM * 2;
    ushort* AGC_bf = (ushort*)p; p += (size_t)CSZ * DIM * 2;
    ushort* AGL_bf = (ushort*)p; p += (size_t)LSZ * DIM * 2;
    ushort* L2L_bf = (ushort*)p; p += (size_t)LSZ * DIM * 2;
    ushort* l_bf0  = (ushort*)p; p += (size_t)LSZ * DIM * 2;
    ushort* l_bf1  = (ushort*)p; p += (size_t)LSZ * DIM * 2;
    ushort* c_bf0  = (ushort*)p; p += (size_t)CSZ * DIM * 2;
    ushort* c_bf1  = (ushort*)p; p += (size_t)CSZ * DIM * 2;
    ushort* Wt     = (ushort*)p; p += (size_t)11 * CH * 2;
    float* W1csr = (float*)p; p += (size_t)ESZ * 4;
    float* W2e   = (float*)p; p += (size_t)ESZ * 4;
    float* pc1 = (float*)p; p += (size_t)CSZ * 4;
    float* qc2 = (float*)p; p += (size_t)CSZ * 4;
    float* ql1 = (float*)p; p += (size_t)LSZ * 4;
    float* pl2 = (float*)p; p += (size_t)LSZ * 4;
    float* D1  = (float*)p; p += (size_t)CSZ * 4;
    float* D2  = (float*)p; p += (size_t)CSZ * 4;
    unsigned* base_c   = (unsigned*)p; p += (size_t)(CSZ + 1) * 4;
    unsigned* base_l   = (unsigned*)p; p += (size_t)(LSZ + 1) * 4;
    unsigned* cur_c    = (unsigned*)p; p += (size_t)CSZ * 4;
    unsigned* cur_l    = (unsigned*)p; p += (size_t)LSZ * 4;
    unsigned* cnt_comb = (unsigned*)p; p += (size_t)(CSZ + LSZ) * 4;
    unsigned* scr_comb = (unsigned*)p; p += (size_t)(CSZ + LSZ) * 4;
    unsigned* perm_c = (unsigned*)p; p += (size_t)ESZ * 4;
    unsigned* perm_l = (unsigned*)p; p += (size_t)ESZ * 4;
    unsigned* le_csr = (unsigned*)p; p += (size_t)ESZ * 4;
    unsigned* ce_csr = (unsigned*)p; p += (size_t)ESZ * 4;
    unsigned* bsum   = (unsigned*)p; p += 1024 * 4;

    const int GL64 = (LSZ + 63) / 64;      // 1563
    const int GC64 = (CSZ + 63) / 64;      // 3282
    const int GE_THR = (ESZ + 255) / 256;
    const int GC_THR = (CSZ + 255) / 256;
    const int GC_WAVE = (CSZ + 3) / 4;
    const int GL_WAVE = (LSZ + 3) / 4;
    const int NCOMB = CSZ + LSZ;

    // preamble: converts + iter-0 dots, weights, CSR build
    cvt_dot2<<<GL_WAVE + GC_WAVE, 256, 0, stream>>>(l_emb0, c_emb0, l_bf0, c_bf0,
                                                    outL[0], outC[0], l_att, c_att,
                                                    pl2, pc1, GL_WAVE);
    wtrans_all<<<dim3(64, 11), 256, 0, stream>>>(l2c_w1, l2c_w2, c2l_w1, c2l_w2,
                                                 l2l_w1, l2l_w2, c_upd_w, l_upd_w, Wt);
    hipMemsetAsync(cnt_comb, 0, (size_t)NCOMB * sizeof(unsigned), stream);
    hist_kernel<<<GE_THR, 256, 0, stream>>>(le, ce, cnt_comb);
    int nb = (NCOMB + 1023) / 1024;
    scan_partial<<<nb, 256, 0, stream>>>(cnt_comb, scr_comb, bsum, NCOMB);
    scan_top<<<1, 256, 0, stream>>>(bsum, nb);
    scan_fixup<<<(NCOMB + 255) / 256, 256, 0, stream>>>(scr_comb, bsum, base_c, base_l, cur_c, cur_l);
    scatter_kernel<<<GE_THR, 256, 0, stream>>>(le, ce, cur_c, cur_l, perm_c, perm_l, le_csr, ce_csr);

    for (int it = 0; it < 2; ++it) {
        const ushort* l_in = (it == 0) ? l_bf0 : l_bf1;
        const ushort* c_in = (it == 0) ? c_bf0 : c_bf1;

        mega_mlp<<<GL64 + GC64 + GL64, 256, 0, stream>>>(
            l_in, c_in, Wt, l2c_b1, l2c_b2, c2l_b1, c2l_b2, l2l_b1, l2l_b2,
            A_bf, B_bf, L2L_bf, c_att, l_att, ql1, qc2, GL64, GC64);

        fused_softmax<<<GC_THR, 256, 0, stream>>>(base_c, le_csr, perm_c,
                                                  pc1, ql1, pl2, qc2, W1csr, W2e, D1, D2);

        mega_aggr<<<GC_WAVE + GL_WAVE, 256, 0, stream>>>(
            base_c, le_csr, W1csr, D1, A_bf, AGC_bf,
            base_l, ce_csr, perm_l, W2e, D2, B_bf, AGL_bf, GC_WAVE);

        mega_upd<<<GC64 + GL64, 256, 0, stream>>>(
            c_in, AGC_bf, l_in, AGL_bf, L2L_bf, Wt, c_upd_b, l_upd_b,
            outC[it + 1], c_bf1, outL[it + 1], l_bf1,
            c_att, l_att, pc1, pl2, GC64, GL64, (it == 0) ? 1 : 0);
    }
}

// Round 14
// 898.090 us; speedup vs baseline: 1.0627x; 1.0075x over previous
//
#include <hip/hip_runtime.h>

#define DIM 128
#define LSZ 100000
#define CSZ 210000
#define ESZ 630000
#define CH  16384   // ushorts per 128x128 weight chunk

typedef __attribute__((ext_vector_type(8))) short short8;
typedef __attribute__((ext_vector_type(4))) float f32x4;

__device__ __forceinline__ ushort f2b(float x) {          // fp32 -> bf16 RNE
    unsigned u = __float_as_uint(x);
    return (ushort)((u + 0x7FFFu + ((u >> 16) & 1)) >> 16);
}
__device__ __forceinline__ float b2f(unsigned lo16) {
    return __uint_as_float(lo16 << 16);
}
__device__ __forceinline__ int lds_off(int row, int c) {
    return row * 256 + ((c ^ (row & 7)) << 4);
}
__device__ __forceinline__ void gload_lds16(const void* g, void* l) {
    __builtin_amdgcn_global_load_lds(
        (const __attribute__((address_space(1))) unsigned*)g,
        (__attribute__((address_space(3))) unsigned*)l, 16, 0, 0);
}
// REQUIRED before any __syncthreads() that publishes LDS-DMA results.
__device__ __forceinline__ void vm_drain() {
    asm volatile("s_waitcnt vmcnt(0)" ::: "memory");
}

// K=128 inner loop over a 64-row X tile: acc[2][4], 32 MFMA/wave
__device__ __forceinline__ void kloop64(const char* Xs, const char* Ws,
                                        int wr, int wc, int lane, f32x4 (&acc)[2][4])
{
    #pragma unroll
    for (int ks = 0; ks < 4; ++ks) {
        int kc = ks * 4 + (lane >> 4);
        short8 af[2], bfr[4];
        #pragma unroll
        for (int m = 0; m < 2; ++m) {
            int row = wr * 32 + m * 16 + (lane & 15);
            af[m] = *(const short8*)(Xs + lds_off(row, kc));
        }
        #pragma unroll
        for (int n = 0; n < 4; ++n) {
            int col = wc * 64 + n * 16 + (lane & 15);
            bfr[n] = *(const short8*)(Ws + lds_off(col, kc));
        }
        #pragma unroll
        for (int m = 0; m < 2; ++m)
            #pragma unroll
            for (int n = 0; n < 4; ++n)
                acc[m][n] = __builtin_amdgcn_mfma_f32_16x16x32_bf16(af[m], bfr[n], acc[m][n], 0, 0, 0);
    }
}

// stage 64x128 X tile via LDS-DMA (16KB), source pre-swizzled; runtime row-swap
__device__ __forceinline__ void stage_x64(const ushort* __restrict__ G, size_t grow0,
                                          char* L, int wid, int lane, bool swap)
{
    #pragma unroll
    for (int g = 0; g < 4; ++g) {
        int row0 = wid * 16 + g * 4;
        int row  = row0 + (lane >> 4);
        size_t grow = grow0 + (size_t)(swap ? (row ^ 1) : row);
        const ushort* src = G + grow * DIM + (((lane & 15) ^ (row & 7)) << 3);
        gload_lds16(src, L + row0 * 256);
    }
}

// stage 128x128 weight tile via LDS-DMA (32KB)
__device__ __forceinline__ void stage_w128(const ushort* __restrict__ G, char* L,
                                           int wid, int lane)
{
    #pragma unroll
    for (int g = 0; g < 8; ++g) {
        int row0 = wid * 32 + g * 4;
        int row  = row0 + (lane >> 4);
        const ushort* src = G + (size_t)row * DIM + (((lane & 15) ^ (row & 7)) << 3);
        gload_lds16(src, L + row0 * 256);
    }
}

// register-staged boundary X tile (64 rows) with bounds check
__device__ __forceinline__ void stage_x64_slow(const ushort* __restrict__ X, int r0t,
                                               char* Xs, int tid, int M, bool swap)
{
    #pragma unroll
    for (int i = 0; i < 4; ++i) {
        int id = i * 256 + tid;            // 0..1023
        int row = id >> 4, c = id & 15;
        int gr = r0t + row;
        short8 v = {0,0,0,0,0,0,0,0};
        if (gr < M) {
            int sr = swap ? (gr ^ 1) : gr;
            v = *(const short8*)(X + (size_t)sr * DIM + c * 8);
        }
        *(short8*)(Xs + lds_off(row, c)) = v;
    }
}

// register-staged weight tile (always full 128 rows)
__device__ __forceinline__ void stage_w_slow(const ushort* __restrict__ W, char* Ws, int tid)
{
    #pragma unroll
    for (int i = 0; i < 8; ++i) {
        int id = i * 256 + tid;
        int row = id >> 4, c = id & 15;
        *(short8*)(Ws + lds_off(row, c)) = *(const short8*)(W + row * DIM + c * 8);
    }
}

// ---------------------------------------------------------------------------
// 2-layer MLP body, 64-row tile (48KB LDS -> 3 blocks/CU)
// dotout is STRIDE-2: writes dotout[2*gr] (packed per-node dot pairs)
// ---------------------------------------------------------------------------
__device__ __forceinline__ void mlp2_body(char* smem, int bloc,
    const ushort* __restrict__ X,
    const ushort* __restrict__ Wt1, const ushort* __restrict__ Wt2,
    const float* __restrict__ b1, const float* __restrict__ b2,
    ushort* __restrict__ Yb,
    const float* __restrict__ attp, float* __restrict__ dotout,
    int M, bool swap, bool dot)
{
    char* Xs = smem;                       // 16KB
    char* Ws = smem + 16384;               // 32KB
    const int tid  = threadIdx.x;
    const int lane = tid & 63;
    const int wid  = tid >> 6;
    const int wr = wid >> 1, wc = wid & 1;
    const int r0t = bloc * 64;
    const bool full = (r0t + 64 <= M);

    if (full) {
        stage_x64(X, (size_t)r0t, Xs, wid, lane, swap);
        stage_w128(Wt1, Ws, wid, lane);
        vm_drain();
    } else {
        stage_x64_slow(X, r0t, Xs, tid, M, swap);
        stage_w_slow(Wt1, Ws, tid);
    }
    __syncthreads();

    f32x4 acc[2][4];
    #pragma unroll
    for (int m = 0; m < 2; ++m)
        #pragma unroll
        for (int n = 0; n < 4; ++n) acc[m][n] = (f32x4){0.f, 0.f, 0.f, 0.f};

    kloop64(Xs, Ws, wr, wc, lane, acc);
    __syncthreads();                       // all LDS reads of X/W1 done

    // stage W2 via DMA; write H = relu(acc+b1) bf16 into Xs
    stage_w128(Wt2, Ws, wid, lane);
    {
        const int col0 = wc * 64 + (lane & 15);
        float b1v[4];
        #pragma unroll
        for (int n = 0; n < 4; ++n) b1v[n] = b1[col0 + n * 16];
        #pragma unroll
        for (int m = 0; m < 2; ++m)
            #pragma unroll
            for (int i = 0; i < 4; ++i) {
                int row = wr * 32 + m * 16 + (lane >> 4) * 4 + i;
                #pragma unroll
                for (int n = 0; n < 4; ++n) {
                    float v = fmaxf(acc[m][n][i] + b1v[n], 0.f);
                    int cb = (col0 + n * 16) * 2;
                    *(ushort*)(Xs + row * 256 + (((cb >> 4) ^ (row & 7)) << 4) + (cb & 15)) = f2b(v);
                }
            }
    }
    vm_drain();
    __syncthreads();

    #pragma unroll
    for (int m = 0; m < 2; ++m)
        #pragma unroll
        for (int n = 0; n < 4; ++n) acc[m][n] = (f32x4){0.f, 0.f, 0.f, 0.f};

    kloop64(Xs, Ws, wr, wc, lane, acc);

    const int col0 = wc * 64 + (lane & 15);
    float b2v[4], attv[4];
    #pragma unroll
    for (int n = 0; n < 4; ++n) b2v[n] = b2[col0 + n * 16];
    if (dot)
        #pragma unroll
        for (int n = 0; n < 4; ++n) attv[n] = attp[col0 + n * 16];

    float ps[2][4];
    #pragma unroll
    for (int m = 0; m < 2; ++m)
        #pragma unroll
        for (int i = 0; i < 4; ++i) {
            int gr = r0t + wr * 32 + m * 16 + (lane >> 4) * 4 + i;
            float p = 0.f;
            #pragma unroll
            for (int n = 0; n < 4; ++n) {
                float y = acc[m][n][i] + b2v[n];
                if (gr < M) Yb[(size_t)gr * DIM + col0 + n * 16] = f2b(y);
                if (dot) p = fmaf(y, attv[n], p);
            }
            ps[m][i] = p;
        }

    if (dot) {
        #pragma unroll
        for (int mask = 1; mask <= 8; mask <<= 1)
            #pragma unroll
            for (int m = 0; m < 2; ++m)
                #pragma unroll
                for (int i = 0; i < 4; ++i)
                    ps[m][i] += __shfl_xor(ps[m][i], mask);
        __syncthreads();
        float* part = (float*)smem;        // [2][64]
        if ((lane & 15) == 0)
            #pragma unroll
            for (int m = 0; m < 2; ++m)
                #pragma unroll
                for (int i = 0; i < 4; ++i)
                    part[wc * 64 + wr * 32 + m * 16 + (lane >> 4) * 4 + i] = ps[m][i];
        __syncthreads();
        if (tid < 64) {
            int gr = r0t + tid;
            if (gr < M) dotout[2 * (size_t)gr] = part[tid] + part[64 + tid];
        }
    }
}

// ---------------------------------------------------------------------------
// concat-K update GEMM body, 64-row tile; fp32 d_out via NT stores; stride-2 dot
// ---------------------------------------------------------------------------
__device__ __forceinline__ void upd_body(char* smem, int bloc,
    const ushort* __restrict__ X1, const ushort* __restrict__ X2, const ushort* __restrict__ X3,
    int nin, const ushort* __restrict__ Wt, const float* __restrict__ bias,
    float* __restrict__ Yf, ushort* __restrict__ Ybm,
    const float* __restrict__ attp, float* __restrict__ dotout,
    int M, bool writebf, bool dot)
{
    char* Xs = smem;
    char* Ws = smem + 16384;
    const int tid  = threadIdx.x;
    const int lane = tid & 63;
    const int wid  = tid >> 6;
    const int wr = wid >> 1, wc = wid & 1;
    const int r0t = bloc * 64;
    const bool full = (r0t + 64 <= M);

    f32x4 acc[2][4];
    #pragma unroll
    for (int m = 0; m < 2; ++m)
        #pragma unroll
        for (int n = 0; n < 4; ++n) acc[m][n] = (f32x4){0.f, 0.f, 0.f, 0.f};

    for (int in = 0; in < nin; ++in) {
        const ushort* X = (in == 0) ? X1 : ((in == 1) ? X2 : X3);
        __syncthreads();                   // previous kloop's LDS reads done
        if (full) {
            stage_x64(X, (size_t)r0t, Xs, wid, lane, false);
            stage_w128(Wt + (size_t)in * CH, Ws, wid, lane);
            vm_drain();
        } else {
            stage_x64_slow(X, r0t, Xs, tid, M, false);
            stage_w_slow(Wt + (size_t)in * CH, Ws, tid);
        }
        __syncthreads();
        kloop64(Xs, Ws, wr, wc, lane, acc);
    }

    const int col0 = wc * 64 + (lane & 15);
    float bv[4], attv[4];
    #pragma unroll
    for (int n = 0; n < 4; ++n) bv[n] = bias[col0 + n * 16];
    if (dot)
        #pragma unroll
        for (int n = 0; n < 4; ++n) attv[n] = attp[col0 + n * 16];

    float ps[2][4];
    #pragma unroll
    for (int m = 0; m < 2; ++m)
        #pragma unroll
        for (int i = 0; i < 4; ++i) {
            int gr = r0t + wr * 32 + m * 16 + (lane >> 4) * 4 + i;
            float p = 0.f;
            #pragma unroll
            for (int n = 0; n < 4; ++n) {
                float v = acc[m][n][i] + bv[n];
                if (gr < M) {
                    __builtin_nontemporal_store(v, &Yf[(size_t)gr * DIM + col0 + n * 16]);
                    if (writebf) Ybm[(size_t)gr * DIM + col0 + n * 16] = f2b(v);
                }
                if (dot) p = fmaf(v, attv[n], p);
            }
            ps[m][i] = p;
        }

    if (dot) {
        #pragma unroll
        for (int mask = 1; mask <= 8; mask <<= 1)
            #pragma unroll
            for (int m = 0; m < 2; ++m)
                #pragma unroll
                for (int i = 0; i < 4; ++i)
                    ps[m][i] += __shfl_xor(ps[m][i], mask);
        __syncthreads();
        float* part = (float*)smem;
        if ((lane & 15) == 0)
            #pragma unroll
            for (int m = 0; m < 2; ++m)
                #pragma unroll
                for (int i = 0; i < 4; ++i)
                    part[wc * 64 + wr * 32 + m * 16 + (lane >> 4) * 4 + i] = ps[m][i];
        __syncthreads();
        if (tid < 64) {
            int gr = r0t + tid;
            if (gr < M) dotout[2 * (size_t)gr] = part[tid] + part[64 + tid];
        }
    }
}

// ---------------------------------------------------------------------------
// MEGA dispatch 1: all three message MLPs in one grid
// ---------------------------------------------------------------------------
__launch_bounds__(256)
__global__ void mega_mlp(const ushort* __restrict__ l_in, const ushort* __restrict__ c_in,
                         const ushort* __restrict__ Wt,
                         const float* __restrict__ l2c_b1, const float* __restrict__ l2c_b2,
                         const float* __restrict__ c2l_b1, const float* __restrict__ c2l_b2,
                         const float* __restrict__ l2l_b1, const float* __restrict__ l2l_b2,
                         ushort* __restrict__ A_bf, ushort* __restrict__ B_bf,
                         ushort* __restrict__ L2L_bf,
                         const float* __restrict__ c_att, const float* __restrict__ l_att,
                         float* __restrict__ qlpl, float* __restrict__ pcqc,
                         int GL, int GC)
{
    __shared__ char smem[49152];
    int b = blockIdx.x;
    if (b < GL) {
        mlp2_body(smem, b, l_in, Wt + 0 * CH, Wt + 1 * CH, l2c_b1, l2c_b2,
                  A_bf, c_att + DIM, qlpl, LSZ, false, true);          // ql1 -> qlpl[2l]
    } else if (b < GL + GC) {
        mlp2_body(smem, b - GL, c_in, Wt + 2 * CH, Wt + 3 * CH, c2l_b1, c2l_b2,
                  B_bf, l_att + DIM, pcqc + 1, CSZ, false, true);      // qc2 -> pcqc[2c+1]
    } else {
        mlp2_body(smem, b - GL - GC, l_in, Wt + 4 * CH, Wt + 5 * CH, l2l_b1, l2l_b2,
                  L2L_bf, nullptr, nullptr, LSZ, true, false);
    }
}

// ---------------------------------------------------------------------------
// MEGA dispatch 3: both update GEMMs in one grid
// ---------------------------------------------------------------------------
__launch_bounds__(256)
__global__ void mega_upd(const ushort* __restrict__ c_in, const ushort* __restrict__ AGC,
                         const ushort* __restrict__ l_in, const ushort* __restrict__ AGL,
                         const ushort* __restrict__ L2L,
                         const ushort* __restrict__ Wt,
                         const float* __restrict__ c_upd_b, const float* __restrict__ l_upd_b,
                         float* __restrict__ outCf, ushort* __restrict__ c_bf1,
                         float* __restrict__ outLf, ushort* __restrict__ l_bf1,
                         const float* __restrict__ c_att, const float* __restrict__ l_att,
                         float* __restrict__ pcqc, float* __restrict__ qlpl,
                         int GC, int GL, int flags)   // flags!=0 -> writebf+dot
{
    __shared__ char smem[49152];
    int b = blockIdx.x;
    bool wb = flags != 0;
    if (b < GC) {
        upd_body(smem, b, c_in, AGC, nullptr, 2, Wt + 6 * CH, c_upd_b,
                 outCf, c_bf1, c_att, pcqc, CSZ, wb, wb);              // pc1 -> pcqc[2c]
    } else {
        upd_body(smem, b - GC, l_in, AGL, L2L, 3, Wt + 8 * CH, l_upd_b,
                 outLf, l_bf1, l_att, qlpl + 1, LSZ, wb, wb);          // pl2 -> qlpl[2l+1]
    }
}

// ---------------------------------------------------------------------------
// one-time converts
// ---------------------------------------------------------------------------
__launch_bounds__(256)
__global__ void wtrans_all(const float* __restrict__ w0, const float* __restrict__ w1,
                           const float* __restrict__ w2, const float* __restrict__ w3,
                           const float* __restrict__ w4, const float* __restrict__ w5,
                           const float* __restrict__ wcu, const float* __restrict__ wlu,
                           ushort* __restrict__ Wt)
{
    int ch = blockIdx.y;
    const float* W;
    if      (ch == 0) W = w0;
    else if (ch == 1) W = w1;
    else if (ch == 2) W = w2;
    else if (ch == 3) W = w3;
    else if (ch == 4) W = w4;
    else if (ch == 5) W = w5;
    else if (ch == 6) W = wcu;
    else if (ch == 7) W = wcu + 16384;
    else if (ch == 8) W = wlu;
    else if (ch == 9) W = wlu + 16384;
    else              W = wlu + 32768;
    int idx = blockIdx.x * 256 + threadIdx.x;
    int k = idx >> 7, c = idx & 127;
    Wt[(size_t)ch * CH + c * 128 + k] = f2b(W[k * 128 + c]);
}

// merged L+C: fp32 copy (NT) to d_out slot0 + bf16 convert + attention dot (stride-2)
__launch_bounds__(256)
__global__ void cvt_dot2(const float* __restrict__ l_emb, const float* __restrict__ c_emb,
                         ushort* __restrict__ l_bf, ushort* __restrict__ c_bf,
                         float* __restrict__ outLf, float* __restrict__ outCf,
                         const float* __restrict__ l_att, const float* __restrict__ c_att,
                         float* __restrict__ qlpl, float* __restrict__ pcqc, int GLW)
{
    int b = blockIdx.x;
    int wid = threadIdx.x >> 6;
    int lane = threadIdx.x & 63;
    const float* in; ushort* obf; float* of32; const float* att; float* dout; int M; int w;
    if (b < GLW) { in = l_emb; obf = l_bf; of32 = outLf; att = l_att; dout = qlpl + 1; M = LSZ; w = b * 4 + wid; }
    else         { in = c_emb; obf = c_bf; of32 = outCf; att = c_att; dout = pcqc;     M = CSZ; w = (b - GLW) * 4 + wid; }
    if (w >= M) return;
    float2 v = *(const float2*)(in + (size_t)w * DIM + lane * 2);
    __builtin_nontemporal_store(v.x, of32 + (size_t)w * DIM + lane * 2);
    __builtin_nontemporal_store(v.y, of32 + (size_t)w * DIM + lane * 2 + 1);
    ushort ba = f2b(v.x), bb = f2b(v.y);
    *(unsigned*)(obf + (size_t)w * DIM + lane * 2) = (unsigned)ba | ((unsigned)bb << 16);
    float2 a = *(const float2*)(att + lane * 2);
    float s = b2f(ba) * a.x + b2f(bb) * a.y;
    #pragma unroll
    for (int k = 32; k >= 1; k >>= 1) s += __shfl_xor(s, k);
    if (lane == 0) dout[2 * (size_t)w] = s;
}

// ---------------------------------------------------------------------------
// CSR build
// ---------------------------------------------------------------------------
__launch_bounds__(256)
__global__ void hist_kernel(const int* __restrict__ le, const int* __restrict__ ce,
                            unsigned* __restrict__ cnt_comb)
{
    int e = blockIdx.x * blockDim.x + threadIdx.x;
    if (e >= ESZ) return;
    atomicAdd(cnt_comb + ce[e], 1u);
    atomicAdd(cnt_comb + CSZ + le[e], 1u);
}

__launch_bounds__(256)
__global__ void scan_partial(const unsigned* __restrict__ in, unsigned* __restrict__ out,
                             unsigned* __restrict__ bsum, int n)
{
    __shared__ unsigned s[256];
    int tid  = threadIdx.x;
    int base = blockIdx.x * 1024 + tid * 4;
    unsigned v[4];
    #pragma unroll
    for (int k = 0; k < 4; ++k) v[k] = (base + k < n) ? in[base + k] : 0u;
    unsigned tsum = v[0] + v[1] + v[2] + v[3];
    s[tid] = tsum;
    __syncthreads();
    for (int off = 1; off < 256; off <<= 1) {
        unsigned t = (tid >= off) ? s[tid - off] : 0u;
        __syncthreads();
        s[tid] += t;
        __syncthreads();
    }
    unsigned run = s[tid] - tsum;
    #pragma unroll
    for (int k = 0; k < 4; ++k) {
        if (base + k < n) out[base + k] = run;
        run += v[k];
    }
    if (tid == 255) bsum[blockIdx.x] = s[255];
}

__launch_bounds__(256)
__global__ void scan_top(unsigned* __restrict__ bsum, int nb)
{
    __shared__ unsigned s[512];
    int tid = threadIdx.x;
    unsigned v0 = (tid < nb) ? bsum[tid] : 0u;
    unsigned v1 = (tid + 256 < nb) ? bsum[tid + 256] : 0u;
    s[tid] = v0; s[tid + 256] = v1;
    __syncthreads();
    for (int off = 1; off < 512; off <<= 1) {
        unsigned t0 = (tid >= off) ? s[tid - off] : 0u;
        unsigned t1 = (tid + 256 >= off) ? s[tid + 256 - off] : 0u;
        __syncthreads();
        s[tid] += t0; s[tid + 256] += t1;
        __syncthreads();
    }
    if (tid < nb) bsum[tid] = s[tid] - v0;
    if (tid + 256 < nb) bsum[tid + 256] = s[tid + 256] - v1;
}

__launch_bounds__(256)
__global__ void scan_fixup(const unsigned* __restrict__ scr, const unsigned* __restrict__ bsum,
                           unsigned* __restrict__ base_c, unsigned* __restrict__ base_l,
                           unsigned* __restrict__ cur_c, unsigned* __restrict__ cur_l)
{
    int i = blockIdx.x * blockDim.x + threadIdx.x;
    int n = CSZ + LSZ;
    if (i < n) {
        unsigned v = scr[i] + bsum[i >> 10];
        if (i < CSZ) { base_c[i] = v; cur_c[i] = v; }
        else { unsigned b = v - ESZ; base_l[i - CSZ] = b; cur_l[i - CSZ] = b; }
    }
    if (i == 0) { base_c[CSZ] = ESZ; base_l[LSZ] = ESZ; }
}

__launch_bounds__(256)
__global__ void scatter_kernel(const int* __restrict__ le, const int* __restrict__ ce,
                               unsigned* __restrict__ cur_c, unsigned* __restrict__ cur_l,
                               unsigned* __restrict__ perm_c, unsigned* __restrict__ perm_l,
                               unsigned* __restrict__ le_csr, unsigned* __restrict__ ce_csr,
                               unsigned* __restrict__ c_of)
{
    int e = blockIdx.x * blockDim.x + threadIdx.x;
    if (e >= ESZ) return;
    int lv = le[e], cv = ce[e];
    unsigned p1 = atomicAdd(cur_c + cv, 1u);
    perm_c[p1] = (unsigned)e;
    le_csr[p1] = (unsigned)lv;
    c_of[p1]   = (unsigned)cv;
    unsigned p2 = atomicAdd(cur_l + lv, 1u);
    perm_l[p2] = (unsigned)e;
    ce_csr[p2] = (unsigned)cv;
}

// ---------------------------------------------------------------------------
// edge-parallel score in CSR-c order: 1 random 8B gather per edge
// ---------------------------------------------------------------------------
__launch_bounds__(256)
__global__ void edge_score_csr(const unsigned* __restrict__ le_csr, const unsigned* __restrict__ c_of,
                               const float* __restrict__ qlpl, const float* __restrict__ pcqc,
                               float* __restrict__ S1, float* __restrict__ S2)
{
    int j = blockIdx.x * blockDim.x + threadIdx.x;
    if (j >= ESZ) return;
    unsigned lv = le_csr[j], cv = c_of[j];
    float2 lp = *(const float2*)(qlpl + 2 * (size_t)lv);   // (ql1, pl2) - random
    float2 cp = *(const float2*)(pcqc + 2 * (size_t)cv);   // (pc1, qc2) - ~sequential
    float s1 = cp.x + lp.x;  s1 = (s1 > 0.f) ? s1 : 0.2f * s1;
    float s2 = lp.y + cp.y;  s2 = (s2 > 0.f) ? s2 : 0.2f * s2;
    S1[j] = s1;
    S2[j] = s2;
}

// ---------------------------------------------------------------------------
// thread-per-clause streaming softmax (no random gathers); W1csr = S1 in place
// ---------------------------------------------------------------------------
__launch_bounds__(256)
__global__ void fused_softmax(const unsigned* __restrict__ base_c, const unsigned* __restrict__ perm_c,
                              float* __restrict__ S1, float* __restrict__ S2,
                              float* __restrict__ W2e,
                              float* __restrict__ D1, float* __restrict__ D2)
{
    int c = blockIdx.x * blockDim.x + threadIdx.x;
    if (c >= CSZ) return;
    unsigned b0 = base_c[c], b1 = base_c[c + 1];
    float m1 = -1e30f, m2 = -1e30f;
    for (unsigned j = b0; j < b1; ++j) {
        m1 = fmaxf(m1, S1[j]);
        m2 = fmaxf(m2, S2[j]);
    }
    float d1 = 0.f, d2 = 0.f;
    for (unsigned j = b0; j < b1; ++j) {
        float ex1 = __expf(S1[j] - m1);
        float ex2 = __expf(S2[j] - m2);
        d1 += ex1; d2 += ex2;
        S1[j] = ex1;                       // W1csr in place
        W2e[perm_c[j]] = ex2;
    }
    D1[c] = d1; D2[c] = d2;
}

// ---------------------------------------------------------------------------
// MEGA dispatch 2: aggr_c and aggr_l in one grid (wave per node)
// ---------------------------------------------------------------------------
__launch_bounds__(256)
__global__ void mega_aggr(const unsigned* __restrict__ base_c, const unsigned* __restrict__ le_csr,
                          const float* __restrict__ W1csr, const float* __restrict__ D1,
                          const ushort* __restrict__ A_bf, ushort* __restrict__ AGC,
                          const unsigned* __restrict__ base_l, const unsigned* __restrict__ ce_csr,
                          const unsigned* __restrict__ perm_l,
                          const float* __restrict__ W2e, const float* __restrict__ D2,
                          const ushort* __restrict__ B_bf, ushort* __restrict__ AGL,
                          int GCW)
{
    int b = blockIdx.x;
    int wid = threadIdx.x >> 6;
    int lane = threadIdx.x & 63;
    int d = lane * 2;
    if (b < GCW) {
        int w = b * 4 + wid;
        if (w >= CSZ) return;
        unsigned b0 = base_c[w], b1 = base_c[w + 1];
        float invd = 1.f / (D1[w] + 1e-16f);
        float ax = 0.f, ay = 0.f;
        for (unsigned j = b0; j < b1; ++j) {
            float wt = W1csr[j] * invd;
            unsigned lv = le_csr[j];
            unsigned av = *(const unsigned*)(A_bf + (size_t)lv * DIM + d);
            ax = fmaf(wt, b2f(av & 0xffffu), ax);
            ay = fmaf(wt, b2f(av >> 16), ay);
        }
        *(unsigned*)(AGC + (size_t)w * DIM + d) = (unsigned)f2b(ax) | ((unsigned)f2b(ay) << 16);
    } else {
        int w = (b - GCW) * 4 + wid;
        if (w >= LSZ) return;
        unsigned b0 = base_l[w], b1 = base_l[w + 1];
        float ax = 0.f, ay = 0.f;
        for (unsigned j = b0; j < b1; ++j) {
            unsigned e = perm_l[j];
            unsigned cv = ce_csr[j];
            float wt = W2e[e] / (D2[cv] + 1e-16f);
            unsigned bv = *(const unsigned*)(B_bf + (size_t)cv * DIM + d);
            ax = fmaf(wt, b2f(bv & 0xffffu), ax);
            ay = fmaf(wt, b2f(bv >> 16), ay);
        }
        *(unsigned*)(AGL + (size_t)w * DIM + d) = (unsigned)f2b(ax) | ((unsigned)f2b(ay) << 16);
    }
}

extern "C" void kernel_launch(void* const* d_in, const int* in_sizes, int n_in,
                              void* d_out, int out_size, void* d_ws, size_t ws_size,
                              hipStream_t stream)
{
    const int*   le      = (const int*)  d_in[2];
    const int*   ce      = (const int*)  d_in[3];
    const float* l_emb0  = (const float*)d_in[4];
    const float* c_emb0  = (const float*)d_in[5];
    const float* l2c_w1  = (const float*)d_in[6];
    const float* l2c_b1  = (const float*)d_in[7];
    const float* l2c_w2  = (const float*)d_in[8];
    const float* l2c_b2  = (const float*)d_in[9];
    const float* c2l_w1  = (const float*)d_in[10];
    const float* c2l_b1  = (const float*)d_in[11];
    const float* c2l_w2  = (const float*)d_in[12];
    const float* c2l_b2  = (const float*)d_in[13];
    const float* l2l_w1  = (const float*)d_in[14];
    const float* l2l_b1  = (const float*)d_in[15];
    const float* l2l_w2  = (const float*)d_in[16];
    const float* l2l_b2  = (const float*)d_in[17];
    const float* c_att   = (const float*)d_in[18];
    const float* c_upd_w = (const float*)d_in[19];
    const float* c_upd_b = (const float*)d_in[20];
    const float* l_att   = (const float*)d_in[21];
    const float* l_upd_w = (const float*)d_in[22];
    const float* l_upd_b = (const float*)d_in[23];

    float* out = (float*)d_out;
    float* outL[3] = { out,
                       out + (size_t)LSZ * DIM,
                       out + 2 * (size_t)LSZ * DIM };
    float* outC[3] = { out + 3 * (size_t)LSZ * DIM,
                       out + 3 * (size_t)LSZ * DIM + (size_t)CSZ * DIM,
                       out + 3 * (size_t)LSZ * DIM + 2 * (size_t)CSZ * DIM };

    char* p = (char*)d_ws;
    ushort* A_bf   = (ushort*)p; p += (size_t)LSZ * DIM * 2;
    ushort* B_bf   = (ushort*)p; p += (size_t)CSZ * DIM * 2;
    ushort* AGC_bf = (ushort*)p; p += (size_t)CSZ * DIM * 2;
    ushort* AGL_bf = (ushort*)p; p += (size_t)LSZ * DIM * 2;
    ushort* L2L_bf = (ushort*)p; p += (size_t)LSZ * DIM * 2;
    ushort* l_bf0  = (ushort*)p; p += (size_t)LSZ * DIM * 2;
    ushort* l_bf1  = (ushort*)p; p += (size_t)LSZ * DIM * 2;
    ushort* c_bf0  = (ushort*)p; p += (size_t)CSZ * DIM * 2;
    ushort* c_bf1  = (ushort*)p; p += (size_t)CSZ * DIM * 2;
    ushort* Wt     = (ushort*)p; p += (size_t)11 * CH * 2;
    float* W1csr = (float*)p; p += (size_t)ESZ * 4;   // S1 alias (exp in place)
    float* S2buf = (float*)p; p += (size_t)ESZ * 4;
    float* W2e   = (float*)p; p += (size_t)ESZ * 4;
    float* pcqc  = (float*)p; p += (size_t)CSZ * 8;   // packed (pc1, qc2)
    float* qlpl  = (float*)p; p += (size_t)LSZ * 8;   // packed (ql1, pl2)
    float* D1  = (float*)p; p += (size_t)CSZ * 4;
    float* D2  = (float*)p; p += (size_t)CSZ * 4;
    unsigned* base_c   = (unsigned*)p; p += (size_t)(CSZ + 1) * 4;
    unsigned* base_l   = (unsigned*)p; p += (size_t)(LSZ + 1) * 4;
    unsigned* cur_c    = (unsigned*)p; p += (size_t)CSZ * 4;
    unsigned* cur_l    = (unsigned*)p; p += (size_t)LSZ * 4;
    unsigned* cnt_comb = (unsigned*)p; p += (size_t)(CSZ + LSZ) * 4;
    unsigned* scr_comb = (unsigned*)p; p += (size_t)(CSZ + LSZ) * 4;
    unsigned* perm_c = (unsigned*)p; p += (size_t)ESZ * 4;
    unsigned* perm_l = (unsigned*)p; p += (size_t)ESZ * 4;
    unsigned* le_csr = (unsigned*)p; p += (size_t)ESZ * 4;
    unsigned* ce_csr = (unsigned*)p; p += (size_t)ESZ * 4;
    unsigned* c_of   = (unsigned*)p; p += (size_t)ESZ * 4;
    unsigned* bsum   = (unsigned*)p; p += 1024 * 4;

    const int GL64 = (LSZ + 63) / 64;      // 1563
    const int GC64 = (CSZ + 63) / 64;      // 3282
    const int GE_THR = (ESZ + 255) / 256;
    const int GC_THR = (CSZ + 255) / 256;
    const int GC_WAVE = (CSZ + 3) / 4;
    const int GL_WAVE = (LSZ + 3) / 4;
    const int NCOMB = CSZ + LSZ;

    // preamble: converts + iter-0 dots, weights, CSR build
    cvt_dot2<<<GL_WAVE + GC_WAVE, 256, 0, stream>>>(l_emb0, c_emb0, l_bf0, c_bf0,
                                                    outL[0], outC[0], l_att, c_att,
                                                    qlpl, pcqc, GL_WAVE);
    wtrans_all<<<dim3(64, 11), 256, 0, stream>>>(l2c_w1, l2c_w2, c2l_w1, c2l_w2,
                                                 l2l_w1, l2l_w2, c_upd_w, l_upd_w, Wt);
    hipMemsetAsync(cnt_comb, 0, (size_t)NCOMB * sizeof(unsigned), stream);
    hist_kernel<<<GE_THR, 256, 0, stream>>>(le, ce, cnt_comb);
    int nb = (NCOMB + 1023) / 1024;
    scan_partial<<<nb, 256, 0, stream>>>(cnt_comb, scr_comb, bsum, NCOMB);
    scan_top<<<1, 256, 0, stream>>>(bsum, nb);
    scan_fixup<<<(NCOMB + 255) / 256, 256, 0, stream>>>(scr_comb, bsum, base_c, base_l, cur_c, cur_l);
    scatter_kernel<<<GE_THR, 256, 0, stream>>>(le, ce, cur_c, cur_l, perm_c, perm_l,
                                               le_csr, ce_csr, c_of);

    for (int it = 0; it < 2; ++it) {
        const ushort* l_in = (it == 0) ? l_bf0 : l_bf1;
        const ushort* c_in = (it == 0) ? c_bf0 : c_bf1;

        mega_mlp<<<GL64 + GC64 + GL64, 256, 0, stream>>>(
            l_in, c_in, Wt, l2c_b1, l2c_b2, c2l_b1, c2l_b2, l2l_b1, l2l_b2,
            A_bf, B_bf, L2L_bf, c_att, l_att, qlpl, pcqc, GL64, GC64);

        edge_score_csr<<<GE_THR, 256, 0, stream>>>(le_csr, c_of, qlpl, pcqc, W1csr, S2buf);

        fused_softmax<<<GC_THR, 256, 0, stream>>>(base_c, perm_c, W1csr, S2buf, W2e, D1, D2);

        mega_aggr<<<GC_WAVE + GL_WAVE, 256, 0, stream>>>(
            base_c, le_csr, W1csr, D1, A_bf, AGC_bf,
            base_l, ce_csr, perm_l, W2e, D2, B_bf, AGL_bf, GC_WAVE);

        mega_upd<<<GC64 + GL64, 256, 0, stream>>>(
            c_in, AGC_bf, l_in, AGL_bf, L2L_bf, Wt, c_upd_b, l_upd_b,
            outC[it + 1], c_bf1, outL[it + 1], l_bf1,
            c_att, l_att, pcqc, qlpl, GC64, GL64, (it == 0) ? 1 : 0);
    }
}